// Round 10
// baseline (269.155 us; speedup 1.0000x reference)
//
#include <hip/hip_runtime.h>

// TensorConvolutionTrainLayer: S=512,P=196,Q=48,CB=8,R=32,C=10,N=8
// R13: delete the Mt2 round-trip (~150 MB HBM + a 3136-block GEMM). The chain
// builds its own A-tile per k: Ash(k) = Ckt_k(64x48) . x_s^T via 28 MFMAs/block
// (+6% chain MFMA), reading xh2 [s][224][64] f16 (zero-padded rows/cols) from
// L2. Build C-layout lands directly in Ash[ab][p]: col=p=nt*16+fr,
// row=ab=wave*16+fq*4+r. af hoist + cc loop + NS + epilogue = R11 verbatim.
// MtF/MtL now from tiny gemm_fl (896 blocks, 16 Ckt rows x all sp); its pad
// rows are zero via xh2 -> zero_pads deleted. Launches 10 -> 9.

typedef _Float16 half8 __attribute__((ext_vector_type(8)));
typedef _Float16 half4 __attribute__((ext_vector_type(4)));
typedef __fp16   fp16x2 __attribute__((ext_vector_type(2)));
typedef float floatx4 __attribute__((ext_vector_type(4)));

#define KP 224    // P padded to 7*32
#define LDA2 232  // Ash row stride (halfs) = 29 x 16B chunks
#define GSTR 40   // Gsh row stride (halfs): 80B rows -> b128-aligned
#define SSTR 264  // St3 row stride (halfs): 528B, 16B-aligned

__device__ __forceinline__ void gld_lds16(const void* g, void* l) {
  __builtin_amdgcn_global_load_lds((const __attribute__((address_space(1))) void*)g,
                                   (__attribute__((address_space(3))) void*)l, 16, 0, 0);
}

// ---------------- generic MFMA GEMM (MODE 2: stA, MODE 3: GN) ----------------
template<int K, int MODE>
__global__ __launch_bounds__(256)
void gemm_mfma(const _Float16* __restrict__ A, const _Float16* __restrict__ Bt,
               void* __restrict__ out0)
{
  __shared__ __align__(16) _Float16 Ash[128 * 32];
  __shared__ __align__(16) _Float16 Bsh[128 * 32];
  const int tid  = threadIdx.x;
  const int wave = tid >> 6;
  const int lane = tid & 63;
  const int m0 = blockIdx.y * 128;
  const int n0 = blockIdx.x * 128;
  const int wm = (wave >> 1) * 64;
  const int wn = (wave & 1) * 64;
  const int fr = lane & 15;
  const int fq = lane >> 4;

  floatx4 acc[4][4] = {};

  for (int kt = 0; kt < K; kt += 32) {
    __syncthreads();
#pragma unroll
    for (int j = 0; j < 2; j++) {
      const int c   = j * 256 + tid;
      const int row = c >> 2;
      const int ko  = (c & 3) * 8;
      gld_lds16(A  + (size_t)(m0 + row) * K + kt + ko,
                (char*)Ash + (size_t)(j * 256 + wave * 64) * 16);
      gld_lds16(Bt + (size_t)(n0 + row) * K + kt + ko,
                (char*)Bsh + (size_t)(j * 256 + wave * 64) * 16);
    }
    __syncthreads();
    half8 af[4], bf[4];
#pragma unroll
    for (int i = 0; i < 4; i++)
      af[i] = *(const half8*)&Ash[(wm + i * 16 + fr) * 32 + fq * 8];
#pragma unroll
    for (int i = 0; i < 4; i++)
      bf[i] = *(const half8*)&Bsh[(wn + i * 16 + fr) * 32 + fq * 8];
#pragma unroll
    for (int i = 0; i < 4; i++)
#pragma unroll
      for (int j = 0; j < 4; j++)
        acc[i][j] = __builtin_amdgcn_mfma_f32_16x16x32_f16(af[i], bf[j], acc[i][j], 0, 0, 0);
  }

#pragma unroll
  for (int i = 0; i < 4; i++) {
#pragma unroll
    for (int j = 0; j < 4; j++) {
#pragma unroll
      for (int r = 0; r < 4; r++) {
        const int m = m0 + wm + i * 16 + fq * 4 + r;
        const int n = n0 + wn + j * 16 + fr;
        const float v = acc[i][j][r];
        if constexpr (MODE == 2) {
          if (n < 320)
            ((float*)out0)[(size_t)(m & 511) * 2560 + (m >> 9) * 320 + n] = v;
        } else {
          if (n < 32)
            ((float*)out0)[(size_t)m * 32 + n] = v;
        }
      }
    }
  }
}

// ---------------- tiny GEMM for MtF/MtL (first/last conv rows) ----------------
// out[m'=s*224+pp][n=0..15]; n<8 -> MtF[n][s][pp], else MtL[n-8][s][pp].
// xh2 pad rows (pp>=196) are zero -> pad regions come out zero (no zero_pads).
__global__ __launch_bounds__(256)
void gemm_fl(const _Float16* __restrict__ xh2, const _Float16* __restrict__ Ckt,
             _Float16* __restrict__ MtF, _Float16* __restrict__ MtL)
{
  const int tid  = threadIdx.x;
  const int wave = tid >> 6;
  const int lane = tid & 63;
  const int fr = lane & 15;
  const int fq = lane >> 4;
  const int m0 = blockIdx.x * 128;

  const int crow = (fr < 8) ? fr : 384 + fr;   // Ckt rows 0..7 and 392..399
  const half8 b0 = *(const half8*)&Ckt[(size_t)crow * 64 + fq * 8];
  const half8 b1 = *(const half8*)&Ckt[(size_t)crow * 64 + 32 + fq * 8];

#pragma unroll
  for (int t = 0; t < 2; t++) {
    const int mi = wave * 2 + t;
    const int mrow = m0 + mi * 16 + fr;
    const half8 a0 = *(const half8*)&xh2[(size_t)mrow * 64 + fq * 8];
    const half8 a1 = *(const half8*)&xh2[(size_t)mrow * 64 + 32 + fq * 8];
    floatx4 c = {};
    c = __builtin_amdgcn_mfma_f32_16x16x32_f16(a0, b0, c, 0, 0, 0);
    c = __builtin_amdgcn_mfma_f32_16x16x32_f16(a1, b1, c, 0, 0, 0);
    const int m = m0 + mi * 16 + fq * 4;        // multiple of 4; 224%4==0
    const unsigned s = (unsigned)m / 224u;
    const unsigned pp = (unsigned)m - s * 224u; // %4==0, <=220: in-row half4
    half4 h;
#pragma unroll
    for (int r = 0; r < 4; r++) h[r] = (_Float16)c[r];
    if (fr < 8)
      *(half4*)&MtF[((size_t)fr * 512 + s) * KP + pp] = h;
    else
      *(half4*)&MtL[((size_t)(fr - 8) * 512 + s) * KP + pp] = h;
  }
}

// ---------------- fused chain kernel (self-building A-tile) ----------------
__global__ __launch_bounds__(256, 2)
void chain_kernel(const _Float16* __restrict__ xh2, const _Float16* __restrict__ Ckt,
                  const _Float16* __restrict__ Akr, const float* __restrict__ St0,
                  const float* __restrict__ GN, float* __restrict__ out)
{
  __shared__ __align__(16) _Float16 Ash[64 * LDA2];        // 29696 B
  __shared__ __align__(16) _Float16 Gsh[4][64 * GSTR];     // 20480 B (per-wave private)
  __shared__ __align__(16) _Float16 St3[16 * SSTR];        // 8448 B
  __shared__ float oc[10];

  const int tid  = threadIdx.x;
  const int wave = tid >> 6;
  const int lane = tid & 63;
  const int s    = blockIdx.x;
  const int fr   = lane & 15;
  const int fq   = lane >> 4;
  const int fre  = fr & 7;
  const int frh  = fr >> 3;
  const int fqh  = fq >> 1;
  const int fql  = fq & 1;

  // init: St3[c][r*8+sigma(b)] from St0[s][b*320+r*10+c]; tid=(b,r)
  {
    const int b = tid >> 5, r = tid & 31;
    const int kcol = r * 8 + ((b & 1) * 4 + (b >> 1));
    const float* src = St0 + (size_t)s * 2560 + (size_t)tid * 10;
#pragma unroll
    for (int c = 0; c < 10; c++) St3[c * SSTR + kcol] = (_Float16)src[c];
    if (tid < 10) oc[tid] = 0.f;
  }

  // B lane offsets: G B-cols n = ni*16+fr -> l = ni*2+frh, rr = fre (wave's r-slice)
  const size_t lb0 = (size_t)((0 * 2 + frh) * 32 + wave * 8 + fre) * KP + fq * 8;
  const size_t lb1 = (size_t)((1 * 2 + frh) * 32 + wave * 8 + fre) * KP + fq * 8;

  // rolling B prefetch (2-deep): bq[kt&1][ni], preload (k=0, cc=0, kt=0,1)
  half8 bq[2][2];
#pragma unroll
  for (int t2 = 0; t2 < 2; t2++) {
    bq[t2][0] = *(const half8*)(Akr + lb0 + t2 * 32);
    bq[t2][1] = *(const half8*)(Akr + lb1 + t2 * 32);
  }
  const _Float16* xb_base = xh2 + (size_t)s * 224 * 64;
  __syncthreads();   // St3 ready

  _Float16* gw = &Gsh[wave][0];

  for (int k = 0; k < 6; k++) {
    // ---- build Ash(k) = Ckt_k . x_s^T : 28 MFMA/block, C-layout -> Ash[ab][p]
    {
      const _Float16* cb = Ckt + (size_t)(8 + k * 64 + wave * 16 + fr) * 64 + fq * 8;
      const half8 ca0 = *(const half8*)cb;
      const half8 ca1 = *(const half8*)(cb + 32);
#pragma unroll
      for (int nt = 0; nt < 14; nt++) {
        const _Float16* xb = xb_base + (size_t)(nt * 16 + fr) * 64 + fq * 8;
        const half8 xb0 = *(const half8*)xb;
        const half8 xb1 = *(const half8*)(xb + 32);
        floatx4 c = {};
        c = __builtin_amdgcn_mfma_f32_16x16x32_f16(ca0, xb0, c, 0, 0, 0);
        c = __builtin_amdgcn_mfma_f32_16x16x32_f16(ca1, xb1, c, 0, 0, 0);
#pragma unroll
        for (int r = 0; r < 4; r++)
          Ash[(wave * 16 + fq * 4 + r) * LDA2 + nt * 16 + fr] = (_Float16)c[r];
      }
    }
    __syncthreads();   // bar0: Ash(k) complete (also orders St3 epilogue(k-1) writes)

    // af hoist: whole 64x224 A-tile -> regs/AGPRs (R5/R9-proven)
    half8 af[7][4];
#pragma unroll
    for (int kt = 0; kt < 7; kt++)
#pragma unroll
      for (int mi = 0; mi < 4; mi++)
        af[kt][mi] = *(const half8*)&Ash[(mi * 16 + fr) * LDA2 + kt * 32 + fq * 8];
    __syncthreads();   // bar1: af reads done -> Ash free for next k's build

    floatx4 ns[4] = {};

#pragma unroll 1
    for (int cc = 0; cc <= 8; cc++) {
      // ---- early reads for NS(cc-1): old Gsh data; program order places them
      // before this iteration's pack-writes, so a single buffer is safe ----
      half8 aaP[4], bsP;
      if (cc > 0) {
        bsP = *(const half8*)&St3[fr * SSTR + (cc - 1) * 32 + fq * 8];
#pragma unroll
        for (int t = 0; t < 4; t++)
          aaP[t] = *(const half8*)&gw[(t * 16 + fr) * GSTR + fq * 8];
        __builtin_amdgcn_sched_barrier(0);   // pin reads above the G train
      }

      floatx4 acc[4][2] = {};
      if (cc < 8) {
        const _Float16* Bc = Akr + ((size_t)k * 1024 + cc * 128) * KP;
        // ---- G-phase: wave's 64 ab x 32 (4l x own 8r) slice, K=224 ----
#pragma unroll
        for (int kt = 0; kt < 7; kt++) {
#pragma unroll
          for (int mi = 0; mi < 4; mi++) {
            acc[mi][0] = __builtin_amdgcn_mfma_f32_16x16x32_f16(af[kt][mi], bq[kt & 1][0], acc[mi][0], 0, 0, 0);
            acc[mi][1] = __builtin_amdgcn_mfma_f32_16x16x32_f16(af[kt][mi], bq[kt & 1][1], acc[mi][1], 0, 0, 0);
          }
          if (kt < 5) {   // rolling prefetch, distance 2 kt within the chunk
            bq[kt & 1][0] = *(const half8*)(Bc + lb0 + (kt + 2) * 32);
            bq[kt & 1][1] = *(const half8*)(Bc + lb1 + (kt + 2) * 32);
          }
        }
        // refill kt=0,1 of the NEXT chunk; NS+pack below cover the latency
        {
          int ncc = cc + 1, nk = k;
          if (ncc == 8) { ncc = 0; nk = k + 1; }
          if (nk < 6) {
            const _Float16* Bn = Akr + ((size_t)nk * 1024 + ncc * 128) * KP;
#pragma unroll
            for (int t2 = 0; t2 < 2; t2++) {
              bq[t2][0] = *(const half8*)(Bn + lb0 + t2 * 32);
              bq[t2][1] = *(const half8*)(Bn + lb1 + t2 * 32);
            }
          }
        }
      }

      // ---- NS(cc-1): registers ready (read latency covered by G train) ----
      if (cc > 0) {
#pragma unroll
        for (int t = 0; t < 4; t++)
          ns[t] = __builtin_amdgcn_mfma_f32_16x16x32_f16(aaP[t], bsP, ns[t], 0, 0, 0);
      }

      // ---- pack + write cc to PRIVATE Gsh (cvt_pkrtz: 2 f32 -> f16x2) ----
      if (cc < 8) {
#pragma unroll
        for (int ni = 0; ni < 2; ni++)
#pragma unroll
          for (int rg = 0; rg < 4; rg++) {
            union { half4 h4; fp16x2 p[2]; } u;
            u.p[0] = __builtin_amdgcn_cvt_pkrtz(acc[0][ni][rg], acc[1][ni][rg]);
            u.p[1] = __builtin_amdgcn_cvt_pkrtz(acc[2][ni][rg], acc[3][ni][rg]);
            *(half4*)&gw[((fql * 4 + rg) * 8 + fre) * GSTR + (ni * 2 + frh) * 8 + fqh * 4] = u.h4;
          }
      }
    }

    __syncthreads();   // bar2: all NS reads of St3 done before overwrite
    // epilogue: ns -> St3 (wave-disjoint columns). m=t*16+fq*4+rg -> b=m>>3, rr=m&7
    if (fr < 10) {
#pragma unroll
      for (int t = 0; t < 4; t++) {
#pragma unroll
        for (int rg = 0; rg < 4; rg++) {
          const int m = t * 16 + fq * 4 + rg;
          const int b = m >> 3, rr = m & 7;
          St3[fr * SSTR + (wave * 8 + rr) * 8 + (b & 1) * 4 + (b >> 1)] = (_Float16)ns[t][rg];
        }
      }
    }
    // next k's bar0 orders these writes before any NS read of k+1
  }
  __syncthreads();

  // final: out[s,c] = sum_{a,l} St3[c][l*8+sigma(a)] * GN[a][s][l]
  {
    const int a = tid >> 5, l = tid & 31;
    const float gn = GN[((size_t)a * 512 + s) * 32 + l];
    const int kcol = l * 8 + ((a & 1) * 4 + (a >> 1));
#pragma unroll
    for (int c = 0; c < 10; c++) {
      float v = gn * (float)St3[c * SSTR + kcol];
#pragma unroll
      for (int o2 = 1; o2 < 64; o2 <<= 1) v += __shfl_xor(v, o2, 64);
      if (lane == 0) atomicAdd(&oc[c], v);
    }
    __syncthreads();
    if (tid < 10) out[(size_t)s * 10 + tid] = oc[tid];
  }
}

// ---------------- prep kernels ----------------
// xh2 [s][pp 224][64] f16: rows pp>=196 and cols q>=48 zeroed. half8/thread.
__global__ void prep_xh2(const float* __restrict__ x, _Float16* __restrict__ xh2) {
  const int i8 = blockIdx.x * 256 + threadIdx.x;   // 512*224*8 = 917504 threads
  const int q8 = (i8 & 7) * 8;
  const int spp = i8 >> 3;
  const unsigned s = (unsigned)spp / 224u;
  const unsigned pp = (unsigned)spp - s * 224u;
  half8 h = {};
  if (pp < 196 && q8 < 48) {
    const float* src = x + ((size_t)s * 196 + pp) * 48 + q8;
#pragma unroll
    for (int j = 0; j < 8; j++) h[j] = (_Float16)src[j];
  }
  *(half8*)&xh2[(size_t)spp * 64 + q8] = h;
}

__global__ void prep_ckt(const float* __restrict__ cf, const float* __restrict__ cm,
                         const float* __restrict__ cl, _Float16* __restrict__ Ckt) {
  const int idx = blockIdx.x * 256 + threadIdx.x;
  const int q = idx & 63;
  const int row = idx >> 6;
  float v = 0.f;
  if (q < 48) {
    if (row < 8) v = cf[q * 8 + row];
    else if (row < 392) {
      const int rr = row - 8;
      const int k = rr >> 6, ab = rr & 63, a = ab >> 3, b = ab & 7;
      v = cm[((k * 8 + a) * 48 + q) * 8 + b];
    } else if (row < 400) v = cl[(row - 392) * 48 + q];
  }
  Ckt[idx] = (_Float16)v;
}

__global__ void prep_akr(const float* __restrict__ tm, _Float16* __restrict__ Akr) {
  const int idx = blockIdx.x * 256 + threadIdx.x;
  const int p = idx % 224;
  const int lr = (idx / 224) & 1023;
  const int k = idx / (224 * 1024);
  const int l = lr >> 5, r = lr & 31;
  float v = 0.f;
  if (p < 196) v = tm[(((k * 32 + l) * 196) + p) * 32 + r];
  Akr[idx] = (_Float16)v;
}

__global__ void prep_bt0(const float* __restrict__ tf, _Float16* __restrict__ Bt0) {
  const int idx = blockIdx.x * 256 + threadIdx.x;
  const int p = idx % 224;
  const int n = idx / 224;
  float v = 0.f;
  if (n < 320 && p < 196) {
    const int r = n / 10, c = n % 10;
    v = tf[(c * 196 + p) * 32 + r];
  }
  Bt0[idx] = (_Float16)v;
}

__global__ void prep_btl(const float* __restrict__ tl, _Float16* __restrict__ Btl) {
  const int idx = blockIdx.x * 256 + threadIdx.x;
  const int p = idx % 224;
  const int n = idx / 224;
  float v = 0.f;
  if (n < 32 && p < 196) v = tl[n * 196 + p];
  Btl[idx] = (_Float16)v;
}

extern "C" void kernel_launch(void* const* d_in, const int* in_sizes, int n_in,
                              void* d_out, int out_size, void* d_ws, size_t ws_size,
                              hipStream_t stream)
{
  const float* x  = (const float*)d_in[0];
  const float* cf = (const float*)d_in[1];
  const float* cm = (const float*)d_in[2];
  const float* cl = (const float*)d_in[3];
  const float* tf = (const float*)d_in[4];
  const float* tm = (const float*)d_in[5];
  const float* tl = (const float*)d_in[6];
  float* out = (float*)d_out;

  char* w = (char*)d_ws;
  auto alloc = [&](size_t bytes) { char* p = w; w += (bytes + 255) & ~(size_t)255; return p; };
  _Float16* xh2 = (_Float16*)alloc(512ull * 224 * 64 * 2);   // 14.7 MB
  _Float16* Ckt = (_Float16*)alloc(512ull * 64 * 2);
  _Float16* MtF = (_Float16*)alloc(8ull * 512 * KP * 2);
  _Float16* MtL = (_Float16*)alloc(8ull * 512 * KP * 2);
  _Float16* Akr = (_Float16*)alloc(6ull * 1024 * KP * 2);
  _Float16* Bt0 = (_Float16*)alloc(384ull * KP * 2);
  _Float16* Btl = (_Float16*)alloc(128ull * KP * 2);
  float* stA    = (float*)alloc(512ull * 2560 * 4);
  float* GN     = (float*)alloc(4096ull * 32 * 4);
  (void)ws_size; (void)in_sizes; (void)n_in; (void)out_size;

  prep_xh2<<< 3584, 256, 0, stream>>>(x, xh2);
  prep_ckt<<<  128, 256, 0, stream>>>(cf, cm, cl, Ckt);
  prep_akr<<< 5376, 256, 0, stream>>>(tm, Akr);
  prep_bt0<<<  336, 256, 0, stream>>>(tf, Bt0);
  prep_btl<<<  112, 256, 0, stream>>>(tl, Btl);

  gemm_fl <<<  896, 256, 0, stream>>>(xh2, Ckt, MtF, MtL);
  gemm_mfma<KP, 2><<<dim3(3, 32), 256, 0, stream>>>(MtF, Bt0, stA);
  gemm_mfma<KP, 3><<<dim3(1, 32), 256, 0, stream>>>(MtL, Btl, GN);

  chain_kernel<<<512, 256, 0, stream>>>(xh2, Ckt, Akr, stA, GN, out);
}

// Round 12
// 260.150 us; speedup vs baseline: 1.0346x; 1.0346x over previous
//
#include <hip/hip_runtime.h>

// TensorConvolutionTrainLayer: S=512,P=196,Q=48,CB=8,R=32,C=10,N=8
// R14b (resubmit; R14 bench died on container infra, not the kernel).
// R13's in-kernel A-tile build is kept (Mt2 deletion = ~48 us on the
// non-chain side) but its chain spilled (WRITE 32KB->45MB): build temporaries
// + the aaP-across-G-train pipeline exceeded 256 regs. The pipeline was proven
// ~neutral (R9 121.7 vs R11 120.4), so drop it: cc loop reverts to R9's simple
// form (NS ds_reads right before NS MFMAs). Peak live ~216 regs, R9-proven.
//   build: Ash(k) = Ckt_k(64x48) . x_s^T, 28 MFMA/block, C-layout -> Ash[ab][p]
//   G: wave-private 64x32 slice from af (regs) x bq (rolling global prefetch)
//   Gsh wave-private 64x40 -> NS -> St3 epilogue (wave-disjoint columns)

typedef _Float16 half8 __attribute__((ext_vector_type(8)));
typedef _Float16 half4 __attribute__((ext_vector_type(4)));
typedef __fp16   fp16x2 __attribute__((ext_vector_type(2)));
typedef float floatx4 __attribute__((ext_vector_type(4)));

#define KP 224    // P padded to 7*32
#define LDA2 232  // Ash row stride (halfs) = 29 x 16B chunks
#define GSTR 40   // Gsh row stride (halfs): 80B rows -> b128-aligned
#define SSTR 264  // St3 row stride (halfs): 528B, 16B-aligned

__device__ __forceinline__ void gld_lds16(const void* g, void* l) {
  __builtin_amdgcn_global_load_lds((const __attribute__((address_space(1))) void*)g,
                                   (__attribute__((address_space(3))) void*)l, 16, 0, 0);
}

// ---------------- generic MFMA GEMM (MODE 2: stA, MODE 3: GN) ----------------
template<int K, int MODE>
__global__ __launch_bounds__(256)
void gemm_mfma(const _Float16* __restrict__ A, const _Float16* __restrict__ Bt,
               void* __restrict__ out0)
{
  __shared__ __align__(16) _Float16 Ash[128 * 32];
  __shared__ __align__(16) _Float16 Bsh[128 * 32];
  const int tid  = threadIdx.x;
  const int wave = tid >> 6;
  const int lane = tid & 63;
  const int m0 = blockIdx.y * 128;
  const int n0 = blockIdx.x * 128;
  const int wm = (wave >> 1) * 64;
  const int wn = (wave & 1) * 64;
  const int fr = lane & 15;
  const int fq = lane >> 4;

  floatx4 acc[4][4] = {};

  for (int kt = 0; kt < K; kt += 32) {
    __syncthreads();
#pragma unroll
    for (int j = 0; j < 2; j++) {
      const int c   = j * 256 + tid;
      const int row = c >> 2;
      const int ko  = (c & 3) * 8;
      gld_lds16(A  + (size_t)(m0 + row) * K + kt + ko,
                (char*)Ash + (size_t)(j * 256 + wave * 64) * 16);
      gld_lds16(Bt + (size_t)(n0 + row) * K + kt + ko,
                (char*)Bsh + (size_t)(j * 256 + wave * 64) * 16);
    }
    __syncthreads();
    half8 af[4], bf[4];
#pragma unroll
    for (int i = 0; i < 4; i++)
      af[i] = *(const half8*)&Ash[(wm + i * 16 + fr) * 32 + fq * 8];
#pragma unroll
    for (int i = 0; i < 4; i++)
      bf[i] = *(const half8*)&Bsh[(wn + i * 16 + fr) * 32 + fq * 8];
#pragma unroll
    for (int i = 0; i < 4; i++)
#pragma unroll
      for (int j = 0; j < 4; j++)
        acc[i][j] = __builtin_amdgcn_mfma_f32_16x16x32_f16(af[i], bf[j], acc[i][j], 0, 0, 0);
  }

#pragma unroll
  for (int i = 0; i < 4; i++) {
#pragma unroll
    for (int j = 0; j < 4; j++) {
#pragma unroll
      for (int r = 0; r < 4; r++) {
        const int m = m0 + wm + i * 16 + fq * 4 + r;
        const int n = n0 + wn + j * 16 + fr;
        const float v = acc[i][j][r];
        if constexpr (MODE == 2) {
          if (n < 320)
            ((float*)out0)[(size_t)(m & 511) * 2560 + (m >> 9) * 320 + n] = v;
        } else {
          if (n < 32)
            ((float*)out0)[(size_t)m * 32 + n] = v;
        }
      }
    }
  }
}

// ---------------- tiny GEMM for MtF/MtL (first/last conv rows) ----------------
__global__ __launch_bounds__(256)
void gemm_fl(const _Float16* __restrict__ xh2, const _Float16* __restrict__ Ckt,
             _Float16* __restrict__ MtF, _Float16* __restrict__ MtL)
{
  const int tid  = threadIdx.x;
  const int wave = tid >> 6;
  const int lane = tid & 63;
  const int fr = lane & 15;
  const int fq = lane >> 4;
  const int m0 = blockIdx.x * 128;

  const int crow = (fr < 8) ? fr : 384 + fr;   // Ckt rows 0..7 and 392..399
  const half8 b0 = *(const half8*)&Ckt[(size_t)crow * 64 + fq * 8];
  const half8 b1 = *(const half8*)&Ckt[(size_t)crow * 64 + 32 + fq * 8];

#pragma unroll
  for (int t = 0; t < 2; t++) {
    const int mi = wave * 2 + t;
    const int mrow = m0 + mi * 16 + fr;
    const half8 a0 = *(const half8*)&xh2[(size_t)mrow * 64 + fq * 8];
    const half8 a1 = *(const half8*)&xh2[(size_t)mrow * 64 + 32 + fq * 8];
    floatx4 c = {};
    c = __builtin_amdgcn_mfma_f32_16x16x32_f16(a0, b0, c, 0, 0, 0);
    c = __builtin_amdgcn_mfma_f32_16x16x32_f16(a1, b1, c, 0, 0, 0);
    const int m = m0 + mi * 16 + fq * 4;        // multiple of 4; 224%4==0
    const unsigned s = (unsigned)m / 224u;
    const unsigned pp = (unsigned)m - s * 224u; // %4==0, <=220: in-row half4
    half4 h;
#pragma unroll
    for (int r = 0; r < 4; r++) h[r] = (_Float16)c[r];
    if (fr < 8)
      *(half4*)&MtF[((size_t)fr * 512 + s) * KP + pp] = h;
    else
      *(half4*)&MtL[((size_t)(fr - 8) * 512 + s) * KP + pp] = h;
  }
}

// ---------------- fused chain kernel (self-building A-tile, R9 cc loop) ----------------
__global__ __launch_bounds__(256, 2)
void chain_kernel(const _Float16* __restrict__ xh2, const _Float16* __restrict__ Ckt,
                  const _Float16* __restrict__ Akr, const float* __restrict__ St0,
                  const float* __restrict__ GN, float* __restrict__ out)
{
  __shared__ __align__(16) _Float16 Ash[64 * LDA2];        // 29696 B
  __shared__ __align__(16) _Float16 Gsh[4][64 * GSTR];     // 20480 B (per-wave private)
  __shared__ __align__(16) _Float16 St3[16 * SSTR];        // 8448 B
  __shared__ float oc[10];

  const int tid  = threadIdx.x;
  const int wave = tid >> 6;
  const int lane = tid & 63;
  const int s    = blockIdx.x;
  const int fr   = lane & 15;
  const int fq   = lane >> 4;
  const int fre  = fr & 7;
  const int frh  = fr >> 3;
  const int fqh  = fq >> 1;
  const int fql  = fq & 1;

  // init: St3[c][r*8+sigma(b)] from St0[s][b*320+r*10+c]; tid=(b,r)
  {
    const int b = tid >> 5, r = tid & 31;
    const int kcol = r * 8 + ((b & 1) * 4 + (b >> 1));
    const float* src = St0 + (size_t)s * 2560 + (size_t)tid * 10;
#pragma unroll
    for (int c = 0; c < 10; c++) St3[c * SSTR + kcol] = (_Float16)src[c];
    if (tid < 10) oc[tid] = 0.f;
  }

  // B lane offsets: G B-cols n = ni*16+fr -> l = ni*2+frh, rr = fre (wave's r-slice)
  const size_t lb0 = (size_t)((0 * 2 + frh) * 32 + wave * 8 + fre) * KP + fq * 8;
  const size_t lb1 = (size_t)((1 * 2 + frh) * 32 + wave * 8 + fre) * KP + fq * 8;

  // rolling B prefetch (2-deep): bq[kt&1][ni], preload (k=0, cc=0, kt=0,1)
  half8 bq[2][2];
#pragma unroll
  for (int t2 = 0; t2 < 2; t2++) {
    bq[t2][0] = *(const half8*)(Akr + lb0 + t2 * 32);
    bq[t2][1] = *(const half8*)(Akr + lb1 + t2 * 32);
  }
  const _Float16* xb_base = xh2 + (size_t)s * 224 * 64;
  __syncthreads();   // St3 ready

  _Float16* gw = &Gsh[wave][0];

  for (int k = 0; k < 6; k++) {
    // ---- build Ash(k) = Ckt_k . x_s^T : 28 MFMA/block, C-layout -> Ash[ab][p]
    {
      const _Float16* cb = Ckt + (size_t)(8 + k * 64 + wave * 16 + fr) * 64 + fq * 8;
      const half8 ca0 = *(const half8*)cb;
      const half8 ca1 = *(const half8*)(cb + 32);
#pragma unroll
      for (int nt = 0; nt < 14; nt++) {
        const _Float16* xb = xb_base + (size_t)(nt * 16 + fr) * 64 + fq * 8;
        const half8 xb0 = *(const half8*)xb;
        const half8 xb1 = *(const half8*)(xb + 32);
        floatx4 c = {};
        c = __builtin_amdgcn_mfma_f32_16x16x32_f16(ca0, xb0, c, 0, 0, 0);
        c = __builtin_amdgcn_mfma_f32_16x16x32_f16(ca1, xb1, c, 0, 0, 0);
#pragma unroll
        for (int r = 0; r < 4; r++)
          Ash[(wave * 16 + fq * 4 + r) * LDA2 + nt * 16 + fr] = (_Float16)c[r];
      }
    }
    __syncthreads();   // bar0: Ash(k) complete (also orders St3 epilogue(k-1) writes)

    // af hoist: whole 64x224 A-tile -> regs/AGPRs (R5/R9-proven)
    half8 af[7][4];
#pragma unroll
    for (int kt = 0; kt < 7; kt++)
#pragma unroll
      for (int mi = 0; mi < 4; mi++)
        af[kt][mi] = *(const half8*)&Ash[(mi * 16 + fr) * LDA2 + kt * 32 + fq * 8];
    __syncthreads();   // bar1: af reads done -> Ash free for next k's build

    floatx4 ns[4] = {};

#pragma unroll 1
    for (int cc = 0; cc < 8; cc++) {
      // ---- G-phase: wave's 64 ab x 32 (4l x own 8r) slice, K=224 ----
      floatx4 acc[4][2] = {};
      const _Float16* Bc = Akr + ((size_t)k * 1024 + cc * 128) * KP;
#pragma unroll
      for (int kt = 0; kt < 7; kt++) {
#pragma unroll
        for (int mi = 0; mi < 4; mi++) {
          acc[mi][0] = __builtin_amdgcn_mfma_f32_16x16x32_f16(af[kt][mi], bq[kt & 1][0], acc[mi][0], 0, 0, 0);
          acc[mi][1] = __builtin_amdgcn_mfma_f32_16x16x32_f16(af[kt][mi], bq[kt & 1][1], acc[mi][1], 0, 0, 0);
        }
        if (kt < 5) {   // rolling prefetch, distance 2 kt within the chunk
          bq[kt & 1][0] = *(const half8*)(Bc + lb0 + (kt + 2) * 32);
          bq[kt & 1][1] = *(const half8*)(Bc + lb1 + (kt + 2) * 32);
        }
      }
      // refill kt=0,1 of the NEXT chunk; pack+NS below cover the latency
      {
        int ncc = cc + 1, nk = k;
        if (ncc == 8) { ncc = 0; nk = k + 1; }
        if (nk < 6) {
          const _Float16* Bn = Akr + ((size_t)nk * 1024 + ncc * 128) * KP;
#pragma unroll
          for (int t2 = 0; t2 < 2; t2++) {
            bq[t2][0] = *(const half8*)(Bn + lb0 + t2 * 32);
            bq[t2][1] = *(const half8*)(Bn + lb1 + t2 * 32);
          }
        }
      }

      // ---- pack + write to PRIVATE Gsh (cvt_pkrtz: 2 f32 -> f16x2) ----
#pragma unroll
      for (int ni = 0; ni < 2; ni++)
#pragma unroll
        for (int rg = 0; rg < 4; rg++) {
          union { half4 h4; fp16x2 p[2]; } u;
          u.p[0] = __builtin_amdgcn_cvt_pkrtz(acc[0][ni][rg], acc[1][ni][rg]);
          u.p[1] = __builtin_amdgcn_cvt_pkrtz(acc[2][ni][rg], acc[3][ni][rg]);
          *(half4*)&gw[((fql * 4 + rg) * 8 + fre) * GSTR + (ni * 2 + frh) * 8 + fqh * 4] = u.h4;
        }

      // ---- NS: own rows, K=32 window cc (same-wave LDS dep, compiler orders) ----
      const half8 bs = *(const half8*)&St3[fr * SSTR + cc * 32 + fq * 8];
#pragma unroll
      for (int t = 0; t < 4; t++) {
        const half8 aa = *(const half8*)&gw[(t * 16 + fr) * GSTR + fq * 8];
        ns[t] = __builtin_amdgcn_mfma_f32_16x16x32_f16(aa, bs, ns[t], 0, 0, 0);
      }
    }

    __syncthreads();   // bar2: all NS reads of St3 done before overwrite
    // epilogue: ns -> St3 (wave-disjoint columns). m=t*16+fq*4+rg -> b=m>>3, rr=m&7
    if (fr < 10) {
#pragma unroll
      for (int t = 0; t < 4; t++) {
#pragma unroll
        for (int rg = 0; rg < 4; rg++) {
          const int m = t * 16 + fq * 4 + rg;
          const int b = m >> 3, rr = m & 7;
          St3[fr * SSTR + (wave * 8 + rr) * 8 + (b & 1) * 4 + (b >> 1)] = (_Float16)ns[t][rg];
        }
      }
    }
    // next k's bar0 orders these writes before any NS read of k+1
  }
  __syncthreads();

  // final: out[s,c] = sum_{a,l} St3[c][l*8+sigma(a)] * GN[a][s][l]
  {
    const int a = tid >> 5, l = tid & 31;
    const float gn = GN[((size_t)a * 512 + s) * 32 + l];
    const int kcol = l * 8 + ((a & 1) * 4 + (a >> 1));
#pragma unroll
    for (int c = 0; c < 10; c++) {
      float v = gn * (float)St3[c * SSTR + kcol];
#pragma unroll
      for (int o2 = 1; o2 < 64; o2 <<= 1) v += __shfl_xor(v, o2, 64);
      if (lane == 0) atomicAdd(&oc[c], v);
    }
    __syncthreads();
    if (tid < 10) out[(size_t)s * 10 + tid] = oc[tid];
  }
}

// ---------------- prep kernels ----------------
// xh2 [s][pp 224][64] f16: rows pp>=196 and cols q>=48 zeroed. half8/thread.
__global__ void prep_xh2(const float* __restrict__ x, _Float16* __restrict__ xh2) {
  const int i8 = blockIdx.x * 256 + threadIdx.x;   // 512*224*8 = 917504 threads
  const int q8 = (i8 & 7) * 8;
  const int spp = i8 >> 3;
  const unsigned s = (unsigned)spp / 224u;
  const unsigned pp = (unsigned)spp - s * 224u;
  half8 h = {};
  if (pp < 196 && q8 < 48) {
    const float* src = x + ((size_t)s * 196 + pp) * 48 + q8;
#pragma unroll
    for (int j = 0; j < 8; j++) h[j] = (_Float16)src[j];
  }
  *(half8*)&xh2[(size_t)spp * 64 + q8] = h;
}

__global__ void prep_ckt(const float* __restrict__ cf, const float* __restrict__ cm,
                         const float* __restrict__ cl, _Float16* __restrict__ Ckt) {
  const int idx = blockIdx.x * 256 + threadIdx.x;
  const int q = idx & 63;
  const int row = idx >> 6;
  float v = 0.f;
  if (q < 48) {
    if (row < 8) v = cf[q * 8 + row];
    else if (row < 392) {
      const int rr = row - 8;
      const int k = rr >> 6, ab = rr & 63, a = ab >> 3, b = ab & 7;
      v = cm[((k * 8 + a) * 48 + q) * 8 + b];
    } else if (row < 400) v = cl[(row - 392) * 48 + q];
  }
  Ckt[idx] = (_Float16)v;
}

__global__ void prep_akr(const float* __restrict__ tm, _Float16* __restrict__ Akr) {
  const int idx = blockIdx.x * 256 + threadIdx.x;
  const int p = idx % 224;
  const int lr = (idx / 224) & 1023;
  const int k = idx / (224 * 1024);
  const int l = lr >> 5, r = lr & 31;
  float v = 0.f;
  if (p < 196) v = tm[(((k * 32 + l) * 196) + p) * 32 + r];
  Akr[idx] = (_Float16)v;
}

__global__ void prep_bt0(const float* __restrict__ tf, _Float16* __restrict__ Bt0) {
  const int idx = blockIdx.x * 256 + threadIdx.x;
  const int p = idx % 224;
  const int n = idx / 224;
  float v = 0.f;
  if (n < 320 && p < 196) {
    const int r = n / 10, c = n % 10;
    v = tf[(c * 196 + p) * 32 + r];
  }
  Bt0[idx] = (_Float16)v;
}

__global__ void prep_btl(const float* __restrict__ tl, _Float16* __restrict__ Btl) {
  const int idx = blockIdx.x * 256 + threadIdx.x;
  const int p = idx % 224;
  const int n = idx / 224;
  float v = 0.f;
  if (n < 32 && p < 196) v = tl[n * 196 + p];
  Btl[idx] = (_Float16)v;
}

extern "C" void kernel_launch(void* const* d_in, const int* in_sizes, int n_in,
                              void* d_out, int out_size, void* d_ws, size_t ws_size,
                              hipStream_t stream)
{
  const float* x  = (const float*)d_in[0];
  const float* cf = (const float*)d_in[1];
  const float* cm = (const float*)d_in[2];
  const float* cl = (const float*)d_in[3];
  const float* tf = (const float*)d_in[4];
  const float* tm = (const float*)d_in[5];
  const float* tl = (const float*)d_in[6];
  float* out = (float*)d_out;

  char* w = (char*)d_ws;
  auto alloc = [&](size_t bytes) { char* p = w; w += (bytes + 255) & ~(size_t)255; return p; };
  _Float16* xh2 = (_Float16*)alloc(512ull * 224 * 64 * 2);   // 14.7 MB
  _Float16* Ckt = (_Float16*)alloc(512ull * 64 * 2);
  _Float16* MtF = (_Float16*)alloc(8ull * 512 * KP * 2);
  _Float16* MtL = (_Float16*)alloc(8ull * 512 * KP * 2);
  _Float16* Akr = (_Float16*)alloc(6ull * 1024 * KP * 2);
  _Float16* Bt0 = (_Float16*)alloc(384ull * KP * 2);
  _Float16* Btl = (_Float16*)alloc(128ull * KP * 2);
  float* stA    = (float*)alloc(512ull * 2560 * 4);
  float* GN     = (float*)alloc(4096ull * 32 * 4);
  (void)ws_size; (void)in_sizes; (void)n_in; (void)out_size;

  prep_xh2<<< 3584, 256, 0, stream>>>(x, xh2);
  prep_ckt<<<  128, 256, 0, stream>>>(cf, cm, cl, Ckt);
  prep_akr<<< 5376, 256, 0, stream>>>(tm, Akr);
  prep_bt0<<<  336, 256, 0, stream>>>(tf, Bt0);
  prep_btl<<<  112, 256, 0, stream>>>(tl, Btl);

  gemm_fl <<<  896, 256, 0, stream>>>(xh2, Ckt, MtF, MtL);
  gemm_mfma<KP, 2><<<dim3(3, 32), 256, 0, stream>>>(MtF, Bt0, stA);
  gemm_mfma<KP, 3><<<dim3(1, 32), 256, 0, stream>>>(MtL, Btl, GN);

  chain_kernel<<<512, 256, 0, stream>>>(xh2, Ckt, Akr, stA, GN, out);
}

// Round 13
// 238.714 us; speedup vs baseline: 1.1275x; 1.0898x over previous
//
#include <hip/hip_runtime.h>

// TensorConvolutionTrainLayer: S=512,P=196,Q=48,CB=8,R=32,C=10,N=8
// R15: fix R14b's residual spill (WRITE 37MB, ~12 regs/k). Diagnosis:
// VGPR_Count=128 => unified file split 128 arch + 128 AGPR (af+ns in AGPR);
// the fully-unrolled build loop hoists up to 28 in-flight global loads
// (~112 arch VGPRs) > 128 arch budget -> spill. Fix: build loop is manually
// 2-way unrolled with NAMED rolling buffers xqA/xqB (static indices, rule
// #20) under `#pragma unroll 1`: in-flight load state 16 VGPRs, distance-2
// prefetch. Everything else R14b verbatim.
//   build: Ash(k) = Ckt_k(64x48) . x_s^T, 28 MFMA/block, C-layout -> Ash[ab][p]
//   G: wave-private 64x32 slice from af (regs) x bq (rolling global prefetch)
//   Gsh wave-private 64x40 -> NS -> St3 epilogue (wave-disjoint columns)

typedef _Float16 half8 __attribute__((ext_vector_type(8)));
typedef _Float16 half4 __attribute__((ext_vector_type(4)));
typedef __fp16   fp16x2 __attribute__((ext_vector_type(2)));
typedef float floatx4 __attribute__((ext_vector_type(4)));

#define KP 224    // P padded to 7*32
#define LDA2 232  // Ash row stride (halfs) = 29 x 16B chunks
#define GSTR 40   // Gsh row stride (halfs): 80B rows -> b128-aligned
#define SSTR 264  // St3 row stride (halfs): 528B, 16B-aligned

__device__ __forceinline__ void gld_lds16(const void* g, void* l) {
  __builtin_amdgcn_global_load_lds((const __attribute__((address_space(1))) void*)g,
                                   (__attribute__((address_space(3))) void*)l, 16, 0, 0);
}

// ---------------- generic MFMA GEMM (MODE 2: stA, MODE 3: GN) ----------------
template<int K, int MODE>
__global__ __launch_bounds__(256)
void gemm_mfma(const _Float16* __restrict__ A, const _Float16* __restrict__ Bt,
               void* __restrict__ out0)
{
  __shared__ __align__(16) _Float16 Ash[128 * 32];
  __shared__ __align__(16) _Float16 Bsh[128 * 32];
  const int tid  = threadIdx.x;
  const int wave = tid >> 6;
  const int lane = tid & 63;
  const int m0 = blockIdx.y * 128;
  const int n0 = blockIdx.x * 128;
  const int wm = (wave >> 1) * 64;
  const int wn = (wave & 1) * 64;
  const int fr = lane & 15;
  const int fq = lane >> 4;

  floatx4 acc[4][4] = {};

  for (int kt = 0; kt < K; kt += 32) {
    __syncthreads();
#pragma unroll
    for (int j = 0; j < 2; j++) {
      const int c   = j * 256 + tid;
      const int row = c >> 2;
      const int ko  = (c & 3) * 8;
      gld_lds16(A  + (size_t)(m0 + row) * K + kt + ko,
                (char*)Ash + (size_t)(j * 256 + wave * 64) * 16);
      gld_lds16(Bt + (size_t)(n0 + row) * K + kt + ko,
                (char*)Bsh + (size_t)(j * 256 + wave * 64) * 16);
    }
    __syncthreads();
    half8 af[4], bf[4];
#pragma unroll
    for (int i = 0; i < 4; i++)
      af[i] = *(const half8*)&Ash[(wm + i * 16 + fr) * 32 + fq * 8];
#pragma unroll
    for (int i = 0; i < 4; i++)
      bf[i] = *(const half8*)&Bsh[(wn + i * 16 + fr) * 32 + fq * 8];
#pragma unroll
    for (int i = 0; i < 4; i++)
#pragma unroll
      for (int j = 0; j < 4; j++)
        acc[i][j] = __builtin_amdgcn_mfma_f32_16x16x32_f16(af[i], bf[j], acc[i][j], 0, 0, 0);
  }

#pragma unroll
  for (int i = 0; i < 4; i++) {
#pragma unroll
    for (int j = 0; j < 4; j++) {
#pragma unroll
      for (int r = 0; r < 4; r++) {
        const int m = m0 + wm + i * 16 + fq * 4 + r;
        const int n = n0 + wn + j * 16 + fr;
        const float v = acc[i][j][r];
        if constexpr (MODE == 2) {
          if (n < 320)
            ((float*)out0)[(size_t)(m & 511) * 2560 + (m >> 9) * 320 + n] = v;
        } else {
          if (n < 32)
            ((float*)out0)[(size_t)m * 32 + n] = v;
        }
      }
    }
  }
}

// ---------------- tiny GEMM for MtF/MtL (first/last conv rows) ----------------
__global__ __launch_bounds__(256)
void gemm_fl(const _Float16* __restrict__ xh2, const _Float16* __restrict__ Ckt,
             _Float16* __restrict__ MtF, _Float16* __restrict__ MtL)
{
  const int tid  = threadIdx.x;
  const int wave = tid >> 6;
  const int lane = tid & 63;
  const int fr = lane & 15;
  const int fq = lane >> 4;
  const int m0 = blockIdx.x * 128;

  const int crow = (fr < 8) ? fr : 384 + fr;   // Ckt rows 0..7 and 392..399
  const half8 b0 = *(const half8*)&Ckt[(size_t)crow * 64 + fq * 8];
  const half8 b1 = *(const half8*)&Ckt[(size_t)crow * 64 + 32 + fq * 8];

#pragma unroll
  for (int t = 0; t < 2; t++) {
    const int mi = wave * 2 + t;
    const int mrow = m0 + mi * 16 + fr;
    const half8 a0 = *(const half8*)&xh2[(size_t)mrow * 64 + fq * 8];
    const half8 a1 = *(const half8*)&xh2[(size_t)mrow * 64 + 32 + fq * 8];
    floatx4 c = {};
    c = __builtin_amdgcn_mfma_f32_16x16x32_f16(a0, b0, c, 0, 0, 0);
    c = __builtin_amdgcn_mfma_f32_16x16x32_f16(a1, b1, c, 0, 0, 0);
    const int m = m0 + mi * 16 + fq * 4;        // multiple of 4; 224%4==0
    const unsigned s = (unsigned)m / 224u;
    const unsigned pp = (unsigned)m - s * 224u; // %4==0, <=220: in-row half4
    half4 h;
#pragma unroll
    for (int r = 0; r < 4; r++) h[r] = (_Float16)c[r];
    if (fr < 8)
      *(half4*)&MtF[((size_t)fr * 512 + s) * KP + pp] = h;
    else
      *(half4*)&MtL[((size_t)(fr - 8) * 512 + s) * KP + pp] = h;
  }
}

// ---------------- fused chain kernel (self-building A-tile, R9 cc loop) ----------------
__global__ __launch_bounds__(256, 2)
void chain_kernel(const _Float16* __restrict__ xh2, const _Float16* __restrict__ Ckt,
                  const _Float16* __restrict__ Akr, const float* __restrict__ St0,
                  const float* __restrict__ GN, float* __restrict__ out)
{
  __shared__ __align__(16) _Float16 Ash[64 * LDA2];        // 29696 B
  __shared__ __align__(16) _Float16 Gsh[4][64 * GSTR];     // 20480 B (per-wave private)
  __shared__ __align__(16) _Float16 St3[16 * SSTR];        // 8448 B
  __shared__ float oc[10];

  const int tid  = threadIdx.x;
  const int wave = tid >> 6;
  const int lane = tid & 63;
  const int s    = blockIdx.x;
  const int fr   = lane & 15;
  const int fq   = lane >> 4;
  const int fre  = fr & 7;
  const int frh  = fr >> 3;
  const int fqh  = fq >> 1;
  const int fql  = fq & 1;

  // init: St3[c][r*8+sigma(b)] from St0[s][b*320+r*10+c]; tid=(b,r)
  {
    const int b = tid >> 5, r = tid & 31;
    const int kcol = r * 8 + ((b & 1) * 4 + (b >> 1));
    const float* src = St0 + (size_t)s * 2560 + (size_t)tid * 10;
#pragma unroll
    for (int c = 0; c < 10; c++) St3[c * SSTR + kcol] = (_Float16)src[c];
    if (tid < 10) oc[tid] = 0.f;
  }

  // B lane offsets: G B-cols n = ni*16+fr -> l = ni*2+frh, rr = fre (wave's r-slice)
  const size_t lb0 = (size_t)((0 * 2 + frh) * 32 + wave * 8 + fre) * KP + fq * 8;
  const size_t lb1 = (size_t)((1 * 2 + frh) * 32 + wave * 8 + fre) * KP + fq * 8;

  // rolling B prefetch (2-deep): bq[kt&1][ni], preload (k=0, cc=0, kt=0,1)
  half8 bq[2][2];
#pragma unroll
  for (int t2 = 0; t2 < 2; t2++) {
    bq[t2][0] = *(const half8*)(Akr + lb0 + t2 * 32);
    bq[t2][1] = *(const half8*)(Akr + lb1 + t2 * 32);
  }
  const _Float16* xb_base = xh2 + (size_t)s * 224 * 64;
  __syncthreads();   // St3 ready

  _Float16* gw = &Gsh[wave][0];

  for (int k = 0; k < 6; k++) {
    // ---- build Ash(k) = Ckt_k . x_s^T : 28 MFMA/block, C-layout -> Ash[ab][p]
    // #pragma unroll 1 + named rolling buffers: <=4 loads in flight (16 VGPR),
    // NOT 28 (112 VGPR, the R13/R14 spill source).
    {
      const _Float16* cb = Ckt + (size_t)(8 + k * 64 + wave * 16 + fr) * 64 + fq * 8;
      const half8 ca0 = *(const half8*)cb;
      const half8 ca1 = *(const half8*)(cb + 32);
      const _Float16* xr = xb_base + (size_t)fr * 64 + fq * 8;
      half8 xqA0 = *(const half8*)xr;
      half8 xqA1 = *(const half8*)(xr + 32);
      half8 xqB0 = *(const half8*)(xr + 16 * 64);
      half8 xqB1 = *(const half8*)(xr + 16 * 64 + 32);
      const int arow = (wave * 16 + fq * 4) * LDA2 + fr;
#pragma unroll 1
      for (int nt = 0; nt < 14; nt += 2) {
        floatx4 c0 = {};
        c0 = __builtin_amdgcn_mfma_f32_16x16x32_f16(ca0, xqA0, c0, 0, 0, 0);
        c0 = __builtin_amdgcn_mfma_f32_16x16x32_f16(ca1, xqA1, c0, 0, 0, 0);
        if (nt < 12) {   // prefetch nt+2 into A (distance 2)
          const _Float16* xb = xr + (size_t)(nt + 2) * 16 * 64;
          xqA0 = *(const half8*)xb;
          xqA1 = *(const half8*)(xb + 32);
        }
#pragma unroll
        for (int r = 0; r < 4; r++)
          Ash[arow + r * LDA2 + nt * 16] = (_Float16)c0[r];
        floatx4 c1 = {};
        c1 = __builtin_amdgcn_mfma_f32_16x16x32_f16(ca0, xqB0, c1, 0, 0, 0);
        c1 = __builtin_amdgcn_mfma_f32_16x16x32_f16(ca1, xqB1, c1, 0, 0, 0);
        if (nt < 12) {   // prefetch nt+3 into B
          const _Float16* xb = xr + (size_t)(nt + 3) * 16 * 64;
          xqB0 = *(const half8*)xb;
          xqB1 = *(const half8*)(xb + 32);
        }
#pragma unroll
        for (int r = 0; r < 4; r++)
          Ash[arow + r * LDA2 + (nt + 1) * 16] = (_Float16)c1[r];
      }
    }
    __syncthreads();   // bar0: Ash(k) complete (also orders St3 epilogue(k-1) writes)

    // af hoist: whole 64x224 A-tile -> regs/AGPRs (R5/R9-proven)
    half8 af[7][4];
#pragma unroll
    for (int kt = 0; kt < 7; kt++)
#pragma unroll
      for (int mi = 0; mi < 4; mi++)
        af[kt][mi] = *(const half8*)&Ash[(mi * 16 + fr) * LDA2 + kt * 32 + fq * 8];
    __syncthreads();   // bar1: af reads done -> Ash free for next k's build

    floatx4 ns[4] = {};

#pragma unroll 1
    for (int cc = 0; cc < 8; cc++) {
      // ---- G-phase: wave's 64 ab x 32 (4l x own 8r) slice, K=224 ----
      floatx4 acc[4][2] = {};
      const _Float16* Bc = Akr + ((size_t)k * 1024 + cc * 128) * KP;
#pragma unroll
      for (int kt = 0; kt < 7; kt++) {
#pragma unroll
        for (int mi = 0; mi < 4; mi++) {
          acc[mi][0] = __builtin_amdgcn_mfma_f32_16x16x32_f16(af[kt][mi], bq[kt & 1][0], acc[mi][0], 0, 0, 0);
          acc[mi][1] = __builtin_amdgcn_mfma_f32_16x16x32_f16(af[kt][mi], bq[kt & 1][1], acc[mi][1], 0, 0, 0);
        }
        if (kt < 5) {   // rolling prefetch, distance 2 kt within the chunk
          bq[kt & 1][0] = *(const half8*)(Bc + lb0 + (kt + 2) * 32);
          bq[kt & 1][1] = *(const half8*)(Bc + lb1 + (kt + 2) * 32);
        }
      }
      // refill kt=0,1 of the NEXT chunk; pack+NS below cover the latency
      {
        int ncc = cc + 1, nk = k;
        if (ncc == 8) { ncc = 0; nk = k + 1; }
        if (nk < 6) {
          const _Float16* Bn = Akr + ((size_t)nk * 1024 + ncc * 128) * KP;
#pragma unroll
          for (int t2 = 0; t2 < 2; t2++) {
            bq[t2][0] = *(const half8*)(Bn + lb0 + t2 * 32);
            bq[t2][1] = *(const half8*)(Bn + lb1 + t2 * 32);
          }
        }
      }

      // ---- pack + write to PRIVATE Gsh (cvt_pkrtz: 2 f32 -> f16x2) ----
#pragma unroll
      for (int ni = 0; ni < 2; ni++)
#pragma unroll
        for (int rg = 0; rg < 4; rg++) {
          union { half4 h4; fp16x2 p[2]; } u;
          u.p[0] = __builtin_amdgcn_cvt_pkrtz(acc[0][ni][rg], acc[1][ni][rg]);
          u.p[1] = __builtin_amdgcn_cvt_pkrtz(acc[2][ni][rg], acc[3][ni][rg]);
          *(half4*)&gw[((fql * 4 + rg) * 8 + fre) * GSTR + (ni * 2 + frh) * 8 + fqh * 4] = u.h4;
        }

      // ---- NS: own rows, K=32 window cc (same-wave LDS dep, compiler orders) ----
      const half8 bs = *(const half8*)&St3[fr * SSTR + cc * 32 + fq * 8];
#pragma unroll
      for (int t = 0; t < 4; t++) {
        const half8 aa = *(const half8*)&gw[(t * 16 + fr) * GSTR + fq * 8];
        ns[t] = __builtin_amdgcn_mfma_f32_16x16x32_f16(aa, bs, ns[t], 0, 0, 0);
      }
    }

    __syncthreads();   // bar2: all NS reads of St3 done before overwrite
    // epilogue: ns -> St3 (wave-disjoint columns). m=t*16+fq*4+rg -> b=m>>3, rr=m&7
    if (fr < 10) {
#pragma unroll
      for (int t = 0; t < 4; t++) {
#pragma unroll
        for (int rg = 0; rg < 4; rg++) {
          const int m = t * 16 + fq * 4 + rg;
          const int b = m >> 3, rr = m & 7;
          St3[fr * SSTR + (wave * 8 + rr) * 8 + (b & 1) * 4 + (b >> 1)] = (_Float16)ns[t][rg];
        }
      }
    }
    // next k's bar0 orders these writes before any NS read of k+1
  }
  __syncthreads();

  // final: out[s,c] = sum_{a,l} St3[c][l*8+sigma(a)] * GN[a][s][l]
  {
    const int a = tid >> 5, l = tid & 31;
    const float gn = GN[((size_t)a * 512 + s) * 32 + l];
    const int kcol = l * 8 + ((a & 1) * 4 + (a >> 1));
#pragma unroll
    for (int c = 0; c < 10; c++) {
      float v = gn * (float)St3[c * SSTR + kcol];
#pragma unroll
      for (int o2 = 1; o2 < 64; o2 <<= 1) v += __shfl_xor(v, o2, 64);
      if (lane == 0) atomicAdd(&oc[c], v);
    }
    __syncthreads();
    if (tid < 10) out[(size_t)s * 10 + tid] = oc[tid];
  }
}

// ---------------- prep kernels ----------------
// xh2 [s][pp 224][64] f16: rows pp>=196 and cols q>=48 zeroed. half8/thread.
__global__ void prep_xh2(const float* __restrict__ x, _Float16* __restrict__ xh2) {
  const int i8 = blockIdx.x * 256 + threadIdx.x;   // 512*224*8 = 917504 threads
  const int q8 = (i8 & 7) * 8;
  const int spp = i8 >> 3;
  const unsigned s = (unsigned)spp / 224u;
  const unsigned pp = (unsigned)spp - s * 224u;
  half8 h = {};
  if (pp < 196 && q8 < 48) {
    const float* src = x + ((size_t)s * 196 + pp) * 48 + q8;
#pragma unroll
    for (int j = 0; j < 8; j++) h[j] = (_Float16)src[j];
  }
  *(half8*)&xh2[(size_t)spp * 64 + q8] = h;
}

__global__ void prep_ckt(const float* __restrict__ cf, const float* __restrict__ cm,
                         const float* __restrict__ cl, _Float16* __restrict__ Ckt) {
  const int idx = blockIdx.x * 256 + threadIdx.x;
  const int q = idx & 63;
  const int row = idx >> 6;
  float v = 0.f;
  if (q < 48) {
    if (row < 8) v = cf[q * 8 + row];
    else if (row < 392) {
      const int rr = row - 8;
      const int k = rr >> 6, ab = rr & 63, a = ab >> 3, b = ab & 7;
      v = cm[((k * 8 + a) * 48 + q) * 8 + b];
    } else if (row < 400) v = cl[(row - 392) * 48 + q];
  }
  Ckt[idx] = (_Float16)v;
}

__global__ void prep_akr(const float* __restrict__ tm, _Float16* __restrict__ Akr) {
  const int idx = blockIdx.x * 256 + threadIdx.x;
  const int p = idx % 224;
  const int lr = (idx / 224) & 1023;
  const int k = idx / (224 * 1024);
  const int l = lr >> 5, r = lr & 31;
  float v = 0.f;
  if (p < 196) v = tm[(((k * 32 + l) * 196) + p) * 32 + r];
  Akr[idx] = (_Float16)v;
}

__global__ void prep_bt0(const float* __restrict__ tf, _Float16* __restrict__ Bt0) {
  const int idx = blockIdx.x * 256 + threadIdx.x;
  const int p = idx % 224;
  const int n = idx / 224;
  float v = 0.f;
  if (n < 320 && p < 196) {
    const int r = n / 10, c = n % 10;
    v = tf[(c * 196 + p) * 32 + r];
  }
  Bt0[idx] = (_Float16)v;
}

__global__ void prep_btl(const float* __restrict__ tl, _Float16* __restrict__ Btl) {
  const int idx = blockIdx.x * 256 + threadIdx.x;
  const int p = idx % 224;
  const int n = idx / 224;
  float v = 0.f;
  if (n < 32 && p < 196) v = tl[n * 196 + p];
  Btl[idx] = (_Float16)v;
}

extern "C" void kernel_launch(void* const* d_in, const int* in_sizes, int n_in,
                              void* d_out, int out_size, void* d_ws, size_t ws_size,
                              hipStream_t stream)
{
  const float* x  = (const float*)d_in[0];
  const float* cf = (const float*)d_in[1];
  const float* cm = (const float*)d_in[2];
  const float* cl = (const float*)d_in[3];
  const float* tf = (const float*)d_in[4];
  const float* tm = (const float*)d_in[5];
  const float* tl = (const float*)d_in[6];
  float* out = (float*)d_out;

  char* w = (char*)d_ws;
  auto alloc = [&](size_t bytes) { char* p = w; w += (bytes + 255) & ~(size_t)255; return p; };
  _Float16* xh2 = (_Float16*)alloc(512ull * 224 * 64 * 2);   // 14.7 MB
  _Float16* Ckt = (_Float16*)alloc(512ull * 64 * 2);
  _Float16* MtF = (_Float16*)alloc(8ull * 512 * KP * 2);
  _Float16* MtL = (_Float16*)alloc(8ull * 512 * KP * 2);
  _Float16* Akr = (_Float16*)alloc(6ull * 1024 * KP * 2);
  _Float16* Bt0 = (_Float16*)alloc(384ull * KP * 2);
  _Float16* Btl = (_Float16*)alloc(128ull * KP * 2);
  float* stA    = (float*)alloc(512ull * 2560 * 4);
  float* GN     = (float*)alloc(4096ull * 32 * 4);
  (void)ws_size; (void)in_sizes; (void)n_in; (void)out_size;

  prep_xh2<<< 3584, 256, 0, stream>>>(x, xh2);
  prep_ckt<<<  128, 256, 0, stream>>>(cf, cm, cl, Ckt);
  prep_akr<<< 5376, 256, 0, stream>>>(tm, Akr);
  prep_bt0<<<  336, 256, 0, stream>>>(tf, Bt0);
  prep_btl<<<  112, 256, 0, stream>>>(tl, Btl);

  gemm_fl <<<  896, 256, 0, stream>>>(xh2, Ckt, MtF, MtL);
  gemm_mfma<KP, 2><<<dim3(3, 32), 256, 0, stream>>>(MtF, Bt0, stA);
  gemm_mfma<KP, 3><<<dim3(1, 32), 256, 0, stream>>>(MtL, Btl, GN);

  chain_kernel<<<512, 256, 0, stream>>>(xh2, Ckt, Akr, stA, GN, out);
}

// Round 14
// 226.120 us; speedup vs baseline: 1.1903x; 1.0557x over previous
//
#include <hip/hip_runtime.h>

// TensorConvolutionTrainLayer: S=512,P=196,Q=48,CB=8,R=32,C=10,N=8
// R16: two cheap attacks on R15's 238.7 (chain 147 + non-chain 92).
// (a) Launch fusion 9->4: prep_all (5 elementwise preps, block-range
//     dispatch), gemm_fl, gemm_23 (the two small K=224 GEMMs, block-uniform
//     operand select), chain. Non-chain was ~25us work in 8 launches.
// (b) Build stores vectorized: swap MFMA operands (mfma(x,ckt,c)) so the
//     C-layout gives 4 consecutive p at fixed ab row -> one half4 LDS store
//     (14 b64/thread/k vs 56 scalar b16). R15's named rolling buffers kept
//     (anti-spill). Everything else R15 verbatim.

typedef _Float16 half8 __attribute__((ext_vector_type(8)));
typedef _Float16 half4 __attribute__((ext_vector_type(4)));
typedef __fp16   fp16x2 __attribute__((ext_vector_type(2)));
typedef float floatx4 __attribute__((ext_vector_type(4)));

#define KP 224    // P padded to 7*32
#define LDA2 232  // Ash row stride (halfs) = 29 x 16B chunks
#define GSTR 40   // Gsh row stride (halfs): 80B rows -> b128-aligned
#define SSTR 264  // St3 row stride (halfs): 528B, 16B-aligned

__device__ __forceinline__ void gld_lds16(const void* g, void* l) {
  __builtin_amdgcn_global_load_lds((const __attribute__((address_space(1))) void*)g,
                                   (__attribute__((address_space(3))) void*)l, 16, 0, 0);
}

// ---------------- fused small GEMMs: stA (3 n-blocks) + GN (1 n-block) ----------------
__global__ __launch_bounds__(256)
void gemm_23(const _Float16* __restrict__ MtF, const _Float16* __restrict__ Bt0,
             const _Float16* __restrict__ MtL, const _Float16* __restrict__ Btl,
             float* __restrict__ stA, float* __restrict__ GN)
{
  __shared__ __align__(16) _Float16 Ash[128 * 32];
  __shared__ __align__(16) _Float16 Bsh[128 * 32];
  const int tid  = threadIdx.x;
  const int wave = tid >> 6;
  const int lane = tid & 63;
  const bool m2 = blockIdx.x < 3;               // block-uniform
  const _Float16* A  = m2 ? MtF : MtL;
  const _Float16* Bt = m2 ? Bt0 : Btl;
  const int m0 = blockIdx.y * 128;
  const int n0 = m2 ? blockIdx.x * 128 : 0;
  const int wm = (wave >> 1) * 64;
  const int wn = (wave & 1) * 64;
  const int fr = lane & 15;
  const int fq = lane >> 4;

  floatx4 acc[4][4] = {};

  for (int kt = 0; kt < KP; kt += 32) {
    __syncthreads();
#pragma unroll
    for (int j = 0; j < 2; j++) {
      const int c   = j * 256 + tid;
      const int row = c >> 2;
      const int ko  = (c & 3) * 8;
      gld_lds16(A  + (size_t)(m0 + row) * KP + kt + ko,
                (char*)Ash + (size_t)(j * 256 + wave * 64) * 16);
      gld_lds16(Bt + (size_t)(n0 + row) * KP + kt + ko,
                (char*)Bsh + (size_t)(j * 256 + wave * 64) * 16);
    }
    __syncthreads();
    half8 af[4], bf[4];
#pragma unroll
    for (int i = 0; i < 4; i++)
      af[i] = *(const half8*)&Ash[(wm + i * 16 + fr) * 32 + fq * 8];
#pragma unroll
    for (int i = 0; i < 4; i++)
      bf[i] = *(const half8*)&Bsh[(wn + i * 16 + fr) * 32 + fq * 8];
#pragma unroll
    for (int i = 0; i < 4; i++)
#pragma unroll
      for (int j = 0; j < 4; j++)
        acc[i][j] = __builtin_amdgcn_mfma_f32_16x16x32_f16(af[i], bf[j], acc[i][j], 0, 0, 0);
  }

#pragma unroll
  for (int i = 0; i < 4; i++) {
#pragma unroll
    for (int j = 0; j < 4; j++) {
#pragma unroll
      for (int r = 0; r < 4; r++) {
        const int m = m0 + wm + i * 16 + fq * 4 + r;
        const int n = n0 + wn + j * 16 + fr;
        const float v = acc[i][j][r];
        if (m2) {
          if (n < 320) stA[(size_t)(m & 511) * 2560 + (m >> 9) * 320 + n] = v;
        } else {
          if (n < 32) GN[(size_t)m * 32 + n] = v;
        }
      }
    }
  }
}

// ---------------- tiny GEMM for MtF/MtL (first/last conv rows) ----------------
__global__ __launch_bounds__(256)
void gemm_fl(const _Float16* __restrict__ xh2, const _Float16* __restrict__ Ckt,
             _Float16* __restrict__ MtF, _Float16* __restrict__ MtL)
{
  const int tid  = threadIdx.x;
  const int wave = tid >> 6;
  const int lane = tid & 63;
  const int fr = lane & 15;
  const int fq = lane >> 4;
  const int m0 = blockIdx.x * 128;

  const int crow = (fr < 8) ? fr : 384 + fr;   // Ckt rows 0..7 and 392..399
  const half8 b0 = *(const half8*)&Ckt[(size_t)crow * 64 + fq * 8];
  const half8 b1 = *(const half8*)&Ckt[(size_t)crow * 64 + 32 + fq * 8];

#pragma unroll
  for (int t = 0; t < 2; t++) {
    const int mi = wave * 2 + t;
    const int mrow = m0 + mi * 16 + fr;
    const half8 a0 = *(const half8*)&xh2[(size_t)mrow * 64 + fq * 8];
    const half8 a1 = *(const half8*)&xh2[(size_t)mrow * 64 + 32 + fq * 8];
    floatx4 c = {};
    c = __builtin_amdgcn_mfma_f32_16x16x32_f16(a0, b0, c, 0, 0, 0);
    c = __builtin_amdgcn_mfma_f32_16x16x32_f16(a1, b1, c, 0, 0, 0);
    const int m = m0 + mi * 16 + fq * 4;        // multiple of 4; 224%4==0
    const unsigned s = (unsigned)m / 224u;
    const unsigned pp = (unsigned)m - s * 224u; // %4==0, <=220: in-row half4
    half4 h;
#pragma unroll
    for (int r = 0; r < 4; r++) h[r] = (_Float16)c[r];
    if (fr < 8)
      *(half4*)&MtF[((size_t)fr * 512 + s) * KP + pp] = h;
    else
      *(half4*)&MtL[((size_t)(fr - 8) * 512 + s) * KP + pp] = h;
  }
}

// ---------------- fused chain kernel (self-building A-tile, R9 cc loop) ----------------
__global__ __launch_bounds__(256, 2)
void chain_kernel(const _Float16* __restrict__ xh2, const _Float16* __restrict__ Ckt,
                  const _Float16* __restrict__ Akr, const float* __restrict__ St0,
                  const float* __restrict__ GN, float* __restrict__ out)
{
  __shared__ __align__(16) _Float16 Ash[64 * LDA2];        // 29696 B
  __shared__ __align__(16) _Float16 Gsh[4][64 * GSTR];     // 20480 B (per-wave private)
  __shared__ __align__(16) _Float16 St3[16 * SSTR];        // 8448 B
  __shared__ float oc[10];

  const int tid  = threadIdx.x;
  const int wave = tid >> 6;
  const int lane = tid & 63;
  const int s    = blockIdx.x;
  const int fr   = lane & 15;
  const int fq   = lane >> 4;
  const int fre  = fr & 7;
  const int frh  = fr >> 3;
  const int fqh  = fq >> 1;
  const int fql  = fq & 1;

  // init: St3[c][r*8+sigma(b)] from St0[s][b*320+r*10+c]; tid=(b,r)
  {
    const int b = tid >> 5, r = tid & 31;
    const int kcol = r * 8 + ((b & 1) * 4 + (b >> 1));
    const float* src = St0 + (size_t)s * 2560 + (size_t)tid * 10;
#pragma unroll
    for (int c = 0; c < 10; c++) St3[c * SSTR + kcol] = (_Float16)src[c];
    if (tid < 10) oc[tid] = 0.f;
  }

  // B lane offsets: G B-cols n = ni*16+fr -> l = ni*2+frh, rr = fre (wave's r-slice)
  const size_t lb0 = (size_t)((0 * 2 + frh) * 32 + wave * 8 + fre) * KP + fq * 8;
  const size_t lb1 = (size_t)((1 * 2 + frh) * 32 + wave * 8 + fre) * KP + fq * 8;

  // rolling B prefetch (2-deep): bq[kt&1][ni], preload (k=0, cc=0, kt=0,1)
  half8 bq[2][2];
#pragma unroll
  for (int t2 = 0; t2 < 2; t2++) {
    bq[t2][0] = *(const half8*)(Akr + lb0 + t2 * 32);
    bq[t2][1] = *(const half8*)(Akr + lb1 + t2 * 32);
  }
  const _Float16* xb_base = xh2 + (size_t)s * 224 * 64;
  __syncthreads();   // St3 ready

  _Float16* gw = &Gsh[wave][0];

  for (int k = 0; k < 6; k++) {
    // ---- build Ash(k) = x_s . Ckt_k^T : 28 MFMA/wave, swapped operands so
    // C-layout gives 4 consecutive p at fixed ab=wave*16+fr -> half4 stores.
    // #pragma unroll 1 + named rolling buffers: <=4 loads in flight (R15).
    {
      const _Float16* cb = Ckt + (size_t)(8 + k * 64 + wave * 16 + fr) * 64 + fq * 8;
      const half8 ca0 = *(const half8*)cb;
      const half8 ca1 = *(const half8*)(cb + 32);
      const _Float16* xr = xb_base + (size_t)fr * 64 + fq * 8;
      half8 xqA0 = *(const half8*)xr;
      half8 xqA1 = *(const half8*)(xr + 32);
      half8 xqB0 = *(const half8*)(xr + 16 * 64);
      half8 xqB1 = *(const half8*)(xr + 16 * 64 + 32);
      const int arow = (wave * 16 + fr) * LDA2 + fq * 4;   // row=ab, col base=fq*4
#pragma unroll 1
      for (int nt = 0; nt < 14; nt += 2) {
        floatx4 c0 = {};
        c0 = __builtin_amdgcn_mfma_f32_16x16x32_f16(xqA0, ca0, c0, 0, 0, 0);
        c0 = __builtin_amdgcn_mfma_f32_16x16x32_f16(xqA1, ca1, c0, 0, 0, 0);
        if (nt < 12) {   // prefetch nt+2 into A (distance 2)
          const _Float16* xb = xr + (size_t)(nt + 2) * 16 * 64;
          xqA0 = *(const half8*)xb;
          xqA1 = *(const half8*)(xb + 32);
        }
        {
          half4 h;
#pragma unroll
          for (int r = 0; r < 4; r++) h[r] = (_Float16)c0[r];
          *(half4*)&Ash[arow + nt * 16] = h;
        }
        floatx4 c1 = {};
        c1 = __builtin_amdgcn_mfma_f32_16x16x32_f16(xqB0, ca0, c1, 0, 0, 0);
        c1 = __builtin_amdgcn_mfma_f32_16x16x32_f16(xqB1, ca1, c1, 0, 0, 0);
        if (nt < 12) {   // prefetch nt+3 into B
          const _Float16* xb = xr + (size_t)(nt + 3) * 16 * 64;
          xqB0 = *(const half8*)xb;
          xqB1 = *(const half8*)(xb + 32);
        }
        {
          half4 h;
#pragma unroll
          for (int r = 0; r < 4; r++) h[r] = (_Float16)c1[r];
          *(half4*)&Ash[arow + (nt + 1) * 16] = h;
        }
      }
    }
    __syncthreads();   // bar0: Ash(k) complete (also orders St3 epilogue(k-1) writes)

    // af hoist: whole 64x224 A-tile -> regs/AGPRs (R5/R9-proven)
    half8 af[7][4];
#pragma unroll
    for (int kt = 0; kt < 7; kt++)
#pragma unroll
      for (int mi = 0; mi < 4; mi++)
        af[kt][mi] = *(const half8*)&Ash[(mi * 16 + fr) * LDA2 + kt * 32 + fq * 8];
    __syncthreads();   // bar1: af reads done -> Ash free for next k's build

    floatx4 ns[4] = {};

#pragma unroll 1
    for (int cc = 0; cc < 8; cc++) {
      // ---- G-phase: wave's 64 ab x 32 (4l x own 8r) slice, K=224 ----
      floatx4 acc[4][2] = {};
      const _Float16* Bc = Akr + ((size_t)k * 1024 + cc * 128) * KP;
#pragma unroll
      for (int kt = 0; kt < 7; kt++) {
#pragma unroll
        for (int mi = 0; mi < 4; mi++) {
          acc[mi][0] = __builtin_amdgcn_mfma_f32_16x16x32_f16(af[kt][mi], bq[kt & 1][0], acc[mi][0], 0, 0, 0);
          acc[mi][1] = __builtin_amdgcn_mfma_f32_16x16x32_f16(af[kt][mi], bq[kt & 1][1], acc[mi][1], 0, 0, 0);
        }
        if (kt < 5) {   // rolling prefetch, distance 2 kt within the chunk
          bq[kt & 1][0] = *(const half8*)(Bc + lb0 + (kt + 2) * 32);
          bq[kt & 1][1] = *(const half8*)(Bc + lb1 + (kt + 2) * 32);
        }
      }
      // refill kt=0,1 of the NEXT chunk; pack+NS below cover the latency
      {
        int ncc = cc + 1, nk = k;
        if (ncc == 8) { ncc = 0; nk = k + 1; }
        if (nk < 6) {
          const _Float16* Bn = Akr + ((size_t)nk * 1024 + ncc * 128) * KP;
#pragma unroll
          for (int t2 = 0; t2 < 2; t2++) {
            bq[t2][0] = *(const half8*)(Bn + lb0 + t2 * 32);
            bq[t2][1] = *(const half8*)(Bn + lb1 + t2 * 32);
          }
        }
      }

      // ---- pack + write to PRIVATE Gsh (cvt_pkrtz: 2 f32 -> f16x2) ----
#pragma unroll
      for (int ni = 0; ni < 2; ni++)
#pragma unroll
        for (int rg = 0; rg < 4; rg++) {
          union { half4 h4; fp16x2 p[2]; } u;
          u.p[0] = __builtin_amdgcn_cvt_pkrtz(acc[0][ni][rg], acc[1][ni][rg]);
          u.p[1] = __builtin_amdgcn_cvt_pkrtz(acc[2][ni][rg], acc[3][ni][rg]);
          *(half4*)&gw[((fql * 4 + rg) * 8 + fre) * GSTR + (ni * 2 + frh) * 8 + fqh * 4] = u.h4;
        }

      // ---- NS: own rows, K=32 window cc (same-wave LDS dep, compiler orders) ----
      const half8 bs = *(const half8*)&St3[fr * SSTR + cc * 32 + fq * 8];
#pragma unroll
      for (int t = 0; t < 4; t++) {
        const half8 aa = *(const half8*)&gw[(t * 16 + fr) * GSTR + fq * 8];
        ns[t] = __builtin_amdgcn_mfma_f32_16x16x32_f16(aa, bs, ns[t], 0, 0, 0);
      }
    }

    __syncthreads();   // bar2: all NS reads of St3 done before overwrite
    // epilogue: ns -> St3 (wave-disjoint columns). m=t*16+fq*4+rg -> b=m>>3, rr=m&7
    if (fr < 10) {
#pragma unroll
      for (int t = 0; t < 4; t++) {
#pragma unroll
        for (int rg = 0; rg < 4; rg++) {
          const int m = t * 16 + fq * 4 + rg;
          const int b = m >> 3, rr = m & 7;
          St3[fr * SSTR + (wave * 8 + rr) * 8 + (b & 1) * 4 + (b >> 1)] = (_Float16)ns[t][rg];
        }
      }
    }
    // next k's bar0 orders these writes before any NS read of k+1
  }
  __syncthreads();

  // final: out[s,c] = sum_{a,l} St3[c][l*8+sigma(a)] * GN[a][s][l]
  {
    const int a = tid >> 5, l = tid & 31;
    const float gn = GN[((size_t)a * 512 + s) * 32 + l];
    const int kcol = l * 8 + ((a & 1) * 4 + (a >> 1));
#pragma unroll
    for (int c = 0; c < 10; c++) {
      float v = gn * (float)St3[c * SSTR + kcol];
#pragma unroll
      for (int o2 = 1; o2 < 64; o2 <<= 1) v += __shfl_xor(v, o2, 64);
      if (lane == 0) atomicAdd(&oc[c], v);
    }
    __syncthreads();
    if (tid < 10) out[(size_t)s * 10 + tid] = oc[tid];
  }
}

// ---------------- fused prep kernel (block-range dispatch) ----------------
// ranges: [0,3584) xh2 | [3584,3712) ckt | [3712,9088) akr | [9088,9424) bt0
//         | [9424,9536) btl
__global__ void prep_all(const float* __restrict__ x, const float* __restrict__ cf,
                         const float* __restrict__ cm, const float* __restrict__ cl,
                         const float* __restrict__ tf, const float* __restrict__ tm,
                         const float* __restrict__ tl,
                         _Float16* __restrict__ xh2, _Float16* __restrict__ Ckt,
                         _Float16* __restrict__ Akr, _Float16* __restrict__ Bt0,
                         _Float16* __restrict__ Btl)
{
  const int bx = blockIdx.x;
  const int tid = threadIdx.x;
  if (bx < 3584) {
    // xh2 [s][pp 224][64] f16: rows pp>=196, cols q>=48 zeroed. half8/thread.
    const int i8 = bx * 256 + tid;
    const int q8 = (i8 & 7) * 8;
    const int spp = i8 >> 3;
    const unsigned s = (unsigned)spp / 224u;
    const unsigned pp = (unsigned)spp - s * 224u;
    half8 h = {};
    if (pp < 196 && q8 < 48) {
      const float* src = x + ((size_t)s * 196 + pp) * 48 + q8;
#pragma unroll
      for (int j = 0; j < 8; j++) h[j] = (_Float16)src[j];
    }
    *(half8*)&xh2[(size_t)spp * 64 + q8] = h;
  } else if (bx < 3712) {
    const int idx = (bx - 3584) * 256 + tid;
    const int q = idx & 63;
    const int row = idx >> 6;
    float v = 0.f;
    if (q < 48) {
      if (row < 8) v = cf[q * 8 + row];
      else if (row < 392) {
        const int rr = row - 8;
        const int k = rr >> 6, ab = rr & 63, a = ab >> 3, b = ab & 7;
        v = cm[((k * 8 + a) * 48 + q) * 8 + b];
      } else if (row < 400) v = cl[(row - 392) * 48 + q];
    }
    Ckt[idx] = (_Float16)v;
  } else if (bx < 9088) {
    const int idx = (bx - 3712) * 256 + tid;
    const int p = idx % 224;
    const int lr = (idx / 224) & 1023;
    const int k = idx / (224 * 1024);
    const int l = lr >> 5, r = lr & 31;
    float v = 0.f;
    if (p < 196) v = tm[(((k * 32 + l) * 196) + p) * 32 + r];
    Akr[idx] = (_Float16)v;
  } else if (bx < 9424) {
    const int idx = (bx - 9088) * 256 + tid;
    const int p = idx % 224;
    const int n = idx / 224;
    float v = 0.f;
    if (n < 320 && p < 196) {
      const int r = n / 10, c = n % 10;
      v = tf[(c * 196 + p) * 32 + r];
    }
    Bt0[idx] = (_Float16)v;
  } else {
    const int idx = (bx - 9424) * 256 + tid;
    const int p = idx % 224;
    const int n = idx / 224;
    float v = 0.f;
    if (n < 32 && p < 196) v = tl[n * 196 + p];
    Btl[idx] = (_Float16)v;
  }
}

extern "C" void kernel_launch(void* const* d_in, const int* in_sizes, int n_in,
                              void* d_out, int out_size, void* d_ws, size_t ws_size,
                              hipStream_t stream)
{
  const float* x  = (const float*)d_in[0];
  const float* cf = (const float*)d_in[1];
  const float* cm = (const float*)d_in[2];
  const float* cl = (const float*)d_in[3];
  const float* tf = (const float*)d_in[4];
  const float* tm = (const float*)d_in[5];
  const float* tl = (const float*)d_in[6];
  float* out = (float*)d_out;

  char* w = (char*)d_ws;
  auto alloc = [&](size_t bytes) { char* p = w; w += (bytes + 255) & ~(size_t)255; return p; };
  _Float16* xh2 = (_Float16*)alloc(512ull * 224 * 64 * 2);   // 14.7 MB
  _Float16* Ckt = (_Float16*)alloc(512ull * 64 * 2);
  _Float16* MtF = (_Float16*)alloc(8ull * 512 * KP * 2);
  _Float16* MtL = (_Float16*)alloc(8ull * 512 * KP * 2);
  _Float16* Akr = (_Float16*)alloc(6ull * 1024 * KP * 2);
  _Float16* Bt0 = (_Float16*)alloc(384ull * KP * 2);
  _Float16* Btl = (_Float16*)alloc(128ull * KP * 2);
  float* stA    = (float*)alloc(512ull * 2560 * 4);
  float* GN     = (float*)alloc(4096ull * 32 * 4);
  (void)ws_size; (void)in_sizes; (void)n_in; (void)out_size;

  prep_all<<< 9536, 256, 0, stream>>>(x, cf, cm, cl, tf, tm, tl,
                                      xh2, Ckt, Akr, Bt0, Btl);
  gemm_fl <<<  896, 256, 0, stream>>>(xh2, Ckt, MtF, MtL);
  gemm_23 <<<dim3(4, 32), 256, 0, stream>>>(MtF, Bt0, MtL, Btl, stA, GN);
  chain_kernel<<<512, 256, 0, stream>>>(xh2, Ckt, Akr, stA, GN, out);
}

// Round 15
// 220.400 us; speedup vs baseline: 1.2212x; 1.0260x over previous
//
#include <hip/hip_runtime.h>

// TensorConvolutionTrainLayer: S=512,P=196,Q=48,CB=8,R=32,C=10,N=8
// R17: fold gemm_fl + gemm_23 into a chain PROLOGUE (launches 4 -> 2).
// Their outputs are per-s only: stA[s] (8x320) -> St3 init, GN[.][s] (8x32)
// -> 1KB LDS GNsh. Per block: Fsh = {16 first/last Ckt rows}.x_s^T (28 MFMA,
// scratch in Gsh region), St3 = Fsh[0:8].Bt0^T (140 MFMA, /10 via mul-shift),
// GNsh = Fsh[8:16].Btl^T (14 MFMA, waves 0-1). Same f32-acc->f16 rounding
// paths as the deleted kernels (absmax invariant). Anti-spill: kt loops are
// unroll-1, <=5 B-loads in flight (R15 discipline). Main loop = R16 verbatim.

typedef _Float16 half8 __attribute__((ext_vector_type(8)));
typedef _Float16 half4 __attribute__((ext_vector_type(4)));
typedef __fp16   fp16x2 __attribute__((ext_vector_type(2)));
typedef float floatx4 __attribute__((ext_vector_type(4)));

#define KP 224    // P padded to 7*32
#define LDA2 232  // Ash row stride (halfs) = 29 x 16B chunks
#define GSTR 40   // Gsh row stride (halfs): 80B rows -> b128-aligned
#define SSTR 264  // St3 row stride (halfs): 528B, 16B-aligned

// ---------------- fused chain kernel (self-contained per-s pipeline) ----------------
__global__ __launch_bounds__(256, 2)
void chain_kernel(const _Float16* __restrict__ xh2, const _Float16* __restrict__ Ckt,
                  const _Float16* __restrict__ Akr, const _Float16* __restrict__ Bt0,
                  const _Float16* __restrict__ Btl, float* __restrict__ out)
{
  __shared__ __align__(16) _Float16 Ash[64 * LDA2];        // 29696 B
  __shared__ __align__(16) _Float16 Gsh[4][64 * GSTR];     // 20480 B (per-wave private; Fsh scratch in prologue)
  __shared__ __align__(16) _Float16 St3[16 * SSTR];        // 8448 B
  __shared__ float GNsh[8][32];                            // 1024 B
  __shared__ float oc[10];

  const int tid  = threadIdx.x;
  const int wave = tid >> 6;
  const int lane = tid & 63;
  const int s    = blockIdx.x;
  const int fr   = lane & 15;
  const int fq   = lane >> 4;
  const int fre  = fr & 7;
  const int frh  = fr >> 3;
  const int fqh  = fq >> 1;
  const int fql  = fq & 1;

  if (tid < 10) oc[tid] = 0.f;

  // B lane offsets: G B-cols n = ni*16+fr -> l = ni*2+frh, rr = fre (wave's r-slice)
  const size_t lb0 = (size_t)((0 * 2 + frh) * 32 + wave * 8 + fre) * KP + fq * 8;
  const size_t lb1 = (size_t)((1 * 2 + frh) * 32 + wave * 8 + fre) * KP + fq * 8;

  // rolling B prefetch (2-deep): bq[kt&1][ni], preload (k=0, cc=0, kt=0,1)
  half8 bq[2][2];
#pragma unroll
  for (int t2 = 0; t2 < 2; t2++) {
    bq[t2][0] = *(const half8*)(Akr + lb0 + t2 * 32);
    bq[t2][1] = *(const half8*)(Akr + lb1 + t2 * 32);
  }
  const _Float16* xb_base = xh2 + (size_t)s * 224 * 64;

  _Float16* Fsh = &Gsh[0][0];   // 16 x LDA2 scratch (7424 B), dead before first gw write

  // ---- prologue A: Fsh[crow 16][p 224] = {Ckt rows 0..7, 392..399} . x_s^T ----
  {
    const int crow = (fr < 8) ? fr : 384 + fr;
    const half8 ca0 = *(const half8*)&Ckt[(size_t)crow * 64 + fq * 8];
    const half8 ca1 = *(const half8*)&Ckt[(size_t)crow * 64 + 32 + fq * 8];
#pragma unroll
    for (int j = 0; j < 4; j++) {
      const int nt = wave + j * 4;              // waves cover nt 0..13
      if (nt < 14) {
        const _Float16* xb = xb_base + (size_t)(nt * 16 + fr) * 64 + fq * 8;
        const half8 xb0 = *(const half8*)xb;
        const half8 xb1 = *(const half8*)(xb + 32);
        floatx4 c = {};
        c = __builtin_amdgcn_mfma_f32_16x16x32_f16(ca0, xb0, c, 0, 0, 0);
        c = __builtin_amdgcn_mfma_f32_16x16x32_f16(ca1, xb1, c, 0, 0, 0);
#pragma unroll
        for (int r = 0; r < 4; r++)
          Fsh[(fq * 4 + r) * LDA2 + nt * 16 + fr] = (_Float16)c[r];
      }
    }
  }
  __syncthreads();   // Fsh complete

  // ---- prologue B: St3[c][r*8+sigma(b)] = Fsh[b] . Bt0[rc]^T  (b<8) ----
  {
    floatx4 pc[5] = {};
#pragma unroll 1
    for (int kt = 0; kt < 7; kt++) {
      const half8 fa = *(const half8*)&Fsh[fr * LDA2 + kt * 32 + fq * 8];
#pragma unroll
      for (int j = 0; j < 5; j++) {
        const int rcrow = (wave * 5 + j) * 16 + fr;    // rc < 320
        const half8 bb = *(const half8*)&Bt0[(size_t)rcrow * KP + kt * 32 + fq * 8];
        pc[j] = __builtin_amdgcn_mfma_f32_16x16x32_f16(fa, bb, pc[j], 0, 0, 0);
      }
    }
    if (fq < 2) {   // C rows 0..7 = b
#pragma unroll
      for (int j = 0; j < 5; j++) {
        const int rc = (wave * 5 + j) * 16 + fr;
        const int r10 = (int)(((unsigned)rc * 205u) >> 11);   // rc/10, exact for rc<320
        const int c = rc - r10 * 10;
#pragma unroll
        for (int ri = 0; ri < 4; ri++) {
          const int b = fq * 4 + ri;
          St3[c * SSTR + r10 * 8 + ((b & 1) * 4 + (b >> 1))] = (_Float16)pc[j][ri];
        }
      }
    }
  }
  // ---- prologue C: GNsh[a][l] = Fsh[8+a] . Btl[l]^T  (waves 0,1) ----
  if (wave < 2) {
    floatx4 gc = {};
#pragma unroll 1
    for (int kt = 0; kt < 7; kt++) {
      const half8 fa = *(const half8*)&Fsh[fr * LDA2 + kt * 32 + fq * 8];
      const half8 bb = *(const half8*)&Btl[(size_t)(wave * 16 + fr) * KP + kt * 32 + fq * 8];
      gc = __builtin_amdgcn_mfma_f32_16x16x32_f16(fa, bb, gc, 0, 0, 0);
    }
    if (fq >= 2) {   // C rows 8..15 -> a = fq*4+ri-8
#pragma unroll
      for (int ri = 0; ri < 4; ri++)
        GNsh[(fq - 2) * 4 + ri][wave * 16 + fr] = gc[ri];
    }
  }
  // no barrier needed here: k=0's bar0 (below) orders St3/GNsh writes and the
  // last Fsh reads before any consumer (NS reads St3 post-bar0; gw writes post-bar1).

  _Float16* gw = &Gsh[wave][0];

  for (int k = 0; k < 6; k++) {
    // ---- build Ash(k) = x_s . Ckt_k^T : 28 MFMA/block, C-layout -> Ash[ab][p]
    // (4 consecutive p at fixed ab -> half4 stores); named rolling buffers.
    {
      const _Float16* cb = Ckt + (size_t)(8 + k * 64 + wave * 16 + fr) * 64 + fq * 8;
      const half8 ca0 = *(const half8*)cb;
      const half8 ca1 = *(const half8*)(cb + 32);
      const _Float16* xr = xb_base + (size_t)fr * 64 + fq * 8;
      half8 xqA0 = *(const half8*)xr;
      half8 xqA1 = *(const half8*)(xr + 32);
      half8 xqB0 = *(const half8*)(xr + 16 * 64);
      half8 xqB1 = *(const half8*)(xr + 16 * 64 + 32);
      const int arow = (wave * 16 + fr) * LDA2 + fq * 4;   // row=ab, col base=fq*4
#pragma unroll 1
      for (int nt = 0; nt < 14; nt += 2) {
        floatx4 c0 = {};
        c0 = __builtin_amdgcn_mfma_f32_16x16x32_f16(xqA0, ca0, c0, 0, 0, 0);
        c0 = __builtin_amdgcn_mfma_f32_16x16x32_f16(xqA1, ca1, c0, 0, 0, 0);
        if (nt < 12) {   // prefetch nt+2 into A (distance 2)
          const _Float16* xb = xr + (size_t)(nt + 2) * 16 * 64;
          xqA0 = *(const half8*)xb;
          xqA1 = *(const half8*)(xb + 32);
        }
        {
          half4 h;
#pragma unroll
          for (int r = 0; r < 4; r++) h[r] = (_Float16)c0[r];
          *(half4*)&Ash[arow + nt * 16] = h;
        }
        floatx4 c1 = {};
        c1 = __builtin_amdgcn_mfma_f32_16x16x32_f16(xqB0, ca0, c1, 0, 0, 0);
        c1 = __builtin_amdgcn_mfma_f32_16x16x32_f16(xqB1, ca1, c1, 0, 0, 0);
        if (nt < 12) {   // prefetch nt+3 into B
          const _Float16* xb = xr + (size_t)(nt + 3) * 16 * 64;
          xqB0 = *(const half8*)xb;
          xqB1 = *(const half8*)(xb + 32);
        }
        {
          half4 h;
#pragma unroll
          for (int r = 0; r < 4; r++) h[r] = (_Float16)c1[r];
          *(half4*)&Ash[arow + (nt + 1) * 16] = h;
        }
      }
    }
    __syncthreads();   // bar0: Ash(k) complete; St3(k)/GNsh writes ordered

    // af hoist: whole 64x224 A-tile -> regs/AGPRs (R5/R9-proven)
    half8 af[7][4];
#pragma unroll
    for (int kt = 0; kt < 7; kt++)
#pragma unroll
      for (int mi = 0; mi < 4; mi++)
        af[kt][mi] = *(const half8*)&Ash[(mi * 16 + fr) * LDA2 + kt * 32 + fq * 8];
    __syncthreads();   // bar1: af reads done -> Ash free for next k's build

    floatx4 ns[4] = {};

#pragma unroll 1
    for (int cc = 0; cc < 8; cc++) {
      // ---- G-phase: wave's 64 ab x 32 (4l x own 8r) slice, K=224 ----
      floatx4 acc[4][2] = {};
      const _Float16* Bc = Akr + ((size_t)k * 1024 + cc * 128) * KP;
#pragma unroll
      for (int kt = 0; kt < 7; kt++) {
#pragma unroll
        for (int mi = 0; mi < 4; mi++) {
          acc[mi][0] = __builtin_amdgcn_mfma_f32_16x16x32_f16(af[kt][mi], bq[kt & 1][0], acc[mi][0], 0, 0, 0);
          acc[mi][1] = __builtin_amdgcn_mfma_f32_16x16x32_f16(af[kt][mi], bq[kt & 1][1], acc[mi][1], 0, 0, 0);
        }
        if (kt < 5) {   // rolling prefetch, distance 2 kt within the chunk
          bq[kt & 1][0] = *(const half8*)(Bc + lb0 + (kt + 2) * 32);
          bq[kt & 1][1] = *(const half8*)(Bc + lb1 + (kt + 2) * 32);
        }
      }
      // refill kt=0,1 of the NEXT chunk; pack+NS below cover the latency
      {
        int ncc = cc + 1, nk = k;
        if (ncc == 8) { ncc = 0; nk = k + 1; }
        if (nk < 6) {
          const _Float16* Bn = Akr + ((size_t)nk * 1024 + ncc * 128) * KP;
#pragma unroll
          for (int t2 = 0; t2 < 2; t2++) {
            bq[t2][0] = *(const half8*)(Bn + lb0 + t2 * 32);
            bq[t2][1] = *(const half8*)(Bn + lb1 + t2 * 32);
          }
        }
      }

      // ---- pack + write to PRIVATE Gsh (cvt_pkrtz: 2 f32 -> f16x2) ----
#pragma unroll
      for (int ni = 0; ni < 2; ni++)
#pragma unroll
        for (int rg = 0; rg < 4; rg++) {
          union { half4 h4; fp16x2 p[2]; } u;
          u.p[0] = __builtin_amdgcn_cvt_pkrtz(acc[0][ni][rg], acc[1][ni][rg]);
          u.p[1] = __builtin_amdgcn_cvt_pkrtz(acc[2][ni][rg], acc[3][ni][rg]);
          *(half4*)&gw[((fql * 4 + rg) * 8 + fre) * GSTR + (ni * 2 + frh) * 8 + fqh * 4] = u.h4;
        }

      // ---- NS: own rows, K=32 window cc (same-wave LDS dep, compiler orders) ----
      const half8 bs = *(const half8*)&St3[fr * SSTR + cc * 32 + fq * 8];
#pragma unroll
      for (int t = 0; t < 4; t++) {
        const half8 aa = *(const half8*)&gw[(t * 16 + fr) * GSTR + fq * 8];
        ns[t] = __builtin_amdgcn_mfma_f32_16x16x32_f16(aa, bs, ns[t], 0, 0, 0);
      }
    }

    __syncthreads();   // bar2: all NS reads of St3 done before overwrite
    // epilogue: ns -> St3 (wave-disjoint columns). m=t*16+fq*4+rg -> b=m>>3, rr=m&7
    if (fr < 10) {
#pragma unroll
      for (int t = 0; t < 4; t++) {
#pragma unroll
        for (int rg = 0; rg < 4; rg++) {
          const int m = t * 16 + fq * 4 + rg;
          const int b = m >> 3, rr = m & 7;
          St3[fr * SSTR + (wave * 8 + rr) * 8 + (b & 1) * 4 + (b >> 1)] = (_Float16)ns[t][rg];
        }
      }
    }
    // next k's bar0 orders these writes before any NS read of k+1
  }
  __syncthreads();

  // final: out[s,c] = sum_{a,l} St3[c][l*8+sigma(a)] * GNsh[a][l]
  {
    const int a = tid >> 5, l = tid & 31;
    const float gn = GNsh[a][l];
    const int kcol = l * 8 + ((a & 1) * 4 + (a >> 1));
#pragma unroll
    for (int c = 0; c < 10; c++) {
      float v = gn * (float)St3[c * SSTR + kcol];
#pragma unroll
      for (int o2 = 1; o2 < 64; o2 <<= 1) v += __shfl_xor(v, o2, 64);
      if (lane == 0) atomicAdd(&oc[c], v);
    }
    __syncthreads();
    if (tid < 10) out[(size_t)s * 10 + tid] = oc[tid];
  }
}

// ---------------- fused prep kernel (block-range dispatch) ----------------
// ranges: [0,3584) xh2 | [3584,3712) ckt | [3712,9088) akr | [9088,9424) bt0
//         | [9424,9536) btl
__global__ void prep_all(const float* __restrict__ x, const float* __restrict__ cf,
                         const float* __restrict__ cm, const float* __restrict__ cl,
                         const float* __restrict__ tf, const float* __restrict__ tm,
                         const float* __restrict__ tl,
                         _Float16* __restrict__ xh2, _Float16* __restrict__ Ckt,
                         _Float16* __restrict__ Akr, _Float16* __restrict__ Bt0,
                         _Float16* __restrict__ Btl)
{
  const int bx = blockIdx.x;
  const int tid = threadIdx.x;
  if (bx < 3584) {
    // xh2 [s][pp 224][64] f16: rows pp>=196, cols q>=48 zeroed. half8/thread.
    const int i8 = bx * 256 + tid;
    const int q8 = (i8 & 7) * 8;
    const int spp = i8 >> 3;
    const unsigned s = (unsigned)spp / 224u;
    const unsigned pp = (unsigned)spp - s * 224u;
    half8 h = {};
    if (pp < 196 && q8 < 48) {
      const float* src = x + ((size_t)s * 196 + pp) * 48 + q8;
#pragma unroll
      for (int j = 0; j < 8; j++) h[j] = (_Float16)src[j];
    }
    *(half8*)&xh2[(size_t)spp * 64 + q8] = h;
  } else if (bx < 3712) {
    const int idx = (bx - 3584) * 256 + tid;
    const int q = idx & 63;
    const int row = idx >> 6;
    float v = 0.f;
    if (q < 48) {
      if (row < 8) v = cf[q * 8 + row];
      else if (row < 392) {
        const int rr = row - 8;
        const int k = rr >> 6, ab = rr & 63, a = ab >> 3, b = ab & 7;
        v = cm[((k * 8 + a) * 48 + q) * 8 + b];
      } else if (row < 400) v = cl[(row - 392) * 48 + q];
    }
    Ckt[idx] = (_Float16)v;
  } else if (bx < 9088) {
    const int idx = (bx - 3712) * 256 + tid;
    const int p = idx % 224;
    const int lr = (idx / 224) & 1023;
    const int k = idx / (224 * 1024);
    const int l = lr >> 5, r = lr & 31;
    float v = 0.f;
    if (p < 196) v = tm[(((k * 32 + l) * 196) + p) * 32 + r];
    Akr[idx] = (_Float16)v;
  } else if (bx < 9424) {
    const int idx = (bx - 9088) * 256 + tid;
    const int p = idx % 224;
    const int n = idx / 224;
    float v = 0.f;
    if (n < 320 && p < 196) {
      const int r = n / 10, c = n % 10;
      v = tf[(c * 196 + p) * 32 + r];
    }
    Bt0[idx] = (_Float16)v;
  } else {
    const int idx = (bx - 9424) * 256 + tid;
    const int p = idx % 224;
    const int n = idx / 224;
    float v = 0.f;
    if (n < 32 && p < 196) v = tl[n * 196 + p];
    Btl[idx] = (_Float16)v;
  }
}

extern "C" void kernel_launch(void* const* d_in, const int* in_sizes, int n_in,
                              void* d_out, int out_size, void* d_ws, size_t ws_size,
                              hipStream_t stream)
{
  const float* x  = (const float*)d_in[0];
  const float* cf = (const float*)d_in[1];
  const float* cm = (const float*)d_in[2];
  const float* cl = (const float*)d_in[3];
  const float* tf = (const float*)d_in[4];
  const float* tm = (const float*)d_in[5];
  const float* tl = (const float*)d_in[6];
  float* out = (float*)d_out;

  char* w = (char*)d_ws;
  auto alloc = [&](size_t bytes) { char* p = w; w += (bytes + 255) & ~(size_t)255; return p; };
  _Float16* xh2 = (_Float16*)alloc(512ull * 224 * 64 * 2);   // 14.7 MB
  _Float16* Ckt = (_Float16*)alloc(512ull * 64 * 2);
  _Float16* Akr = (_Float16*)alloc(6ull * 1024 * KP * 2);
  _Float16* Bt0 = (_Float16*)alloc(384ull * KP * 2);
  _Float16* Btl = (_Float16*)alloc(128ull * KP * 2);
  (void)ws_size; (void)in_sizes; (void)n_in; (void)out_size;

  prep_all<<< 9536, 256, 0, stream>>>(x, cf, cm, cl, tf, tm, tl,
                                      xh2, Ckt, Akr, Bt0, Btl);
  chain_kernel<<<512, 256, 0, stream>>>(xh2, Ckt, Akr, Bt0, Btl, out);
}